// Round 10
// baseline (125.316 us; speedup 1.0000x reference)
//
#include <hip/hip_runtime.h>

// C=8, L=4, M=8192, NGEN=16, DEPTH=6, BATCH=4, N=5461
// Level starts: L0:0 L1:1 L2:5 L3:21 L4:85 L5:341 leaves:1365
// Subtree s (0..15) rooted at L2 node 5+s.

// ---- workspace layout (4B units) ----
#define WS_PART   0        // 32768
#define WS_LOGDEN 32768    // 128  [g*8+c]
#define WS_ASP    32896    // 4096 [g*256 + (i*8+k)*4+j]
#define WS_LOGA   36992    // 4096
#define WS_LPI    41088    // 512
#define WS_LSP    41600    // 64
#define WS_BLEAF  41664    // 524288 [g*32768 + p*8 + c]
#define WS_XCHG   565952   // 64*768 per (b,g): [B2 0..128 | Q2 128..256 | B3 256..768]
#define WS_SG     615104   // 64*16*256  per (b,g): [s][t]
#define WS_PG     877248   // 64*16*2    per (b,g): [s][{pB,pPi}]
#define WS_CNT    879296   // 64*2 ints: [bg][{exchange, finalize}]

__device__ __forceinline__ int node_id(int nl, int s) {
    if (nl == 0) return 0;
    if (nl < 5)  return nl;
    if (nl == 5) return 5 + s;
    if (nl < 10) return 21 + 4 * s + (nl - 6);
    if (nl < 26) return 85 + 16 * s + (nl - 10);
    return 341 + 64 * s + (nl - 26);
}

__device__ __forceinline__ float up_tt(const float* bp, const float* aspU) {
    float tt = 0.f;
    #pragma unroll
    for (int j = 0; j < 4; j++) {
        float4 lo = *(const float4*)(bp + j * 8);
        float4 hi = *(const float4*)(bp + j * 8 + 4);
        tt += aspU[0 + j] * lo.x + aspU[4 + j] * lo.y + aspU[8 + j] * lo.z + aspU[12 + j] * lo.w
            + aspU[16 + j] * hi.x + aspU[20 + j] * hi.y + aspU[24 + j] * hi.z + aspU[28 + j] * hi.w;
    }
    return tt;
}

__device__ __forceinline__ void down_u(const float* r8, const float* aspD, float* u) {
    u[0] = u[1] = u[2] = u[3] = 0.f;
    #pragma unroll
    for (int i = 0; i < 8; i++) {
        u[0] += aspD[i * 4 + 0] * r8[i];
        u[1] += aspD[i * 4 + 1] * r8[i];
        u[2] += aspD[i * 4 + 2] * r8[i];
        u[3] += aspD[i * 4 + 3] * r8[i];
    }
}

// ---------------- K1: B logsumexp partials + zero barrier counters ----------------
__global__ __launch_bounds__(256) void k_pre(const float* __restrict__ B, float* __restrict__ ws) {
    const int x = blockIdx.x, t = threadIdx.x;
    const int lane = t & 63, wv = t >> 6;
    __shared__ float s_stage[128];
    if (x < 64 && t < 2) ((int*)ws)[WS_CNT + x * 2 + t] = 0;
    const int cA = x >> 7, chunk = x & 127;
    const float* Bp = B + ((size_t)(cA * 8192) + chunk * 64) * 16;
    float mx = -3.4e38f, sE = 0.f;
    #pragma unroll
    for (int pass = 0; pass < 4; ++pass) {
        const float v = Bp[pass * 256 + t];
        const float nm = fmaxf(mx, v);
        sE = sE * __expf(mx - nm) + __expf(v - nm);
        mx = nm;
    }
    #pragma unroll
    for (int mk = 16; mk <= 32; mk <<= 1) {
        const float om = __shfl_xor(mx, mk), os = __shfl_xor(sE, mk);
        const float nm = fmaxf(mx, om);
        sE = sE * __expf(mx - nm) + os * __expf(om - nm);
        mx = nm;
    }
    if (lane < 16) { s_stage[(wv * 16 + lane) * 2] = mx; s_stage[(wv * 16 + lane) * 2 + 1] = sE; }
    __syncthreads();
    if (t < 16) {
        float M = s_stage[t * 2], S = s_stage[t * 2 + 1];
        #pragma unroll
        for (int w = 1; w < 4; ++w) {
            const float om = s_stage[(w * 16 + t) * 2], os = s_stage[(w * 16 + t) * 2 + 1];
            const float nm = fmaxf(M, om);
            S = S * __expf(M - nm) + os * __expf(om - nm);
            M = nm;
        }
        ws[WS_PART + ((t * 8 + cA) * 128 + chunk) * 2]     = M;
        ws[WS_PART + ((t * 8 + cA) * 128 + chunk) * 2 + 1] = S;
    }
}

// ---------------- K2: params (16 blocks) + bleaf (256 blocks) ----------------
__global__ __launch_bounds__(256) void k_mid(const float* __restrict__ A,
                                             const float* __restrict__ B,
                                             const float* __restrict__ Pi,
                                             const float* __restrict__ SP,
                                             float* __restrict__ ws) {
    const int x = blockIdx.x, t = threadIdx.x;
    if (x >= 256) {
        const int g = x - 256;
        __shared__ float s_st[256], s_expA[256], s_spe[4], s_pie[32];
        if (t < 128) {
            const int c2 = t >> 4, part = t & 15;
            const float* pp = ws + WS_PART + (size_t)(((g * 8 + c2) * 128 + part * 8) * 2);
            float M = -3.4e38f, S = 0.f;
            #pragma unroll
            for (int q = 0; q < 8; ++q) {
                const float om = pp[q * 2], os = pp[q * 2 + 1];
                const float nm = fmaxf(M, om);
                S = S * __expf(M - nm) + os * __expf(om - nm);
                M = nm;
            }
            s_st[t * 2] = M; s_st[t * 2 + 1] = S;
        }
        const float Av = A[t * 16 + g];
        s_expA[t] = __expf(Av);
        if (t < 4) s_spe[t] = __expf(SP[t * 16 + g]);
        if (t >= 32 && t < 64) s_pie[t - 32] = __expf(Pi[(t - 32) * 16 + g]);
        __syncthreads();
        if (t < 8) {
            float M = s_st[(t * 16) * 2], S = s_st[(t * 16) * 2 + 1];
            #pragma unroll
            for (int q = 1; q < 16; ++q) {
                const float om = s_st[(t * 16 + q) * 2], os = s_st[(t * 16 + q) * 2 + 1];
                const float nm = fmaxf(M, om);
                S = S * __expf(M - nm) + os * __expf(om - nm);
                M = nm;
            }
            ws[WS_LOGDEN + g * 8 + t] = M + __logf(S);
        }
        {
            const int kk = (t >> 2) & 7, jj = t & 3;
            float sumA = 0.f;
            #pragma unroll
            for (int i = 0; i < 8; ++i) sumA += s_expA[(i * 8 + kk) * 4 + jj];
            const float sps = s_spe[0] + s_spe[1] + s_spe[2] + s_spe[3];
            ws[WS_ASP + g * 256 + t]  = s_expA[t] / sumA * (s_spe[jj] / sps);
            ws[WS_LOGA + g * 256 + t] = Av - __logf(sumA);
            if (t < 4) ws[WS_LSP + g * 4 + t] = SP[t * 16 + g] - __logf(sps);
            if (t < 32) {
                float ps = 0.f;
                #pragma unroll
                for (int i2 = 0; i2 < 8; ++i2) ps += s_pie[i2 * 4 + (t & 3)];
                ws[WS_LPI + g * 32 + t] = Pi[t * 16 + g] - __logf(ps);
            }
        }
    } else {
        __shared__ float s_ld[128], s_pie[512], s_smpi[512];
        {
            const int pair = t >> 1, half = t & 1;
            const int c = pair >> 4, gg = pair & 15;
            const float* pp = ws + WS_PART + (size_t)(((gg * 8 + c) * 128 + half * 64) * 2);
            float M = -3.4e38f, S = 0.f;
            for (int q = 0; q < 64; ++q) {
                const float om = pp[q * 2], os = pp[q * 2 + 1];
                const float nm = fmaxf(M, om);
                S = S * __expf(M - nm) + os * __expf(om - nm);
                M = nm;
            }
            const float om = __shfl_xor(M, 1), os = __shfl_xor(S, 1);
            const float nm = fmaxf(M, om);
            S = S * __expf(M - nm) + os * __expf(om - nm);
            M = nm;
            if (half == 0) s_ld[c * 16 + gg] = M + __logf(S);
        }
        s_pie[t] = __expf(Pi[t]);
        s_pie[256 + t] = __expf(Pi[256 + t]);
        __syncthreads();
        #pragma unroll
        for (int h = 0; h < 2; ++h) {
            const int idx = h * 256 + t;
            const int jg = idx & 63;
            float ps = 0.f;
            #pragma unroll
            for (int c2 = 0; c2 < 8; ++c2) ps += s_pie[c2 * 64 + jg];
            s_smpi[idx] = s_pie[idx] / ps;
        }
        __syncthreads();
        const int id = x * 256 + t;
        const int g = id & 15, p = id >> 4;
        const int pos = p & 3;
        float vals[8], ssum = 0.f;
        #pragma unroll
        for (int c = 0; c < 8; ++c) {
            const float v = s_smpi[(c * 4 + pos) * 16 + g] *
                __expf(B[((size_t)(c * 8192) + 1365 + p) * 16 + g] - s_ld[c * 16 + g]);
            vals[c] = v; ssum += v;
        }
        const float inv = 1.f / ssum;
        float* o = ws + WS_BLEAF + (size_t)g * 32768 + (size_t)p * 8;
        *(float4*)o       = make_float4(vals[0] * inv, vals[1] * inv, vals[2] * inv, vals[3] * inv);
        *(float4*)(o + 4) = make_float4(vals[4] * inv, vals[5] * inv, vals[6] * inv, vals[7] * inv);
    }
}

// ---------------- K3: fused up + low-contention counter barrier + down + finalize ----------------
__global__ __launch_bounds__(256, 4) void k_tree(const int* __restrict__ labels,
                                                 const float* __restrict__ B,
                                                 float* __restrict__ ws,
                                                 float* __restrict__ out) {
    const int x = blockIdx.x, t = threadIdx.x;
    const int s = x & 15, g = (x >> 4) & 15, b = x >> 8;
    const int c8 = t & 7, lane = t & 63, wv = t >> 6;

    __shared__ __align__(16) float s_blf[2048];   // aliased as epilogue stage after d5
    __shared__ __align__(16) float s_lgb[720];
    __shared__ __align__(16) float s_lgbM[640];   // s==0 only: nodes 5..84
    __shared__ __align__(16) float s_b5[512], s_q5[512], s_r5[512];
    __shared__ __align__(16) float s_b4[128], s_q4[128], s_r4[128];
    __shared__ __align__(16) float s_b3o[32], s_b3a[512], s_q3[32], s_r3[32];
    __shared__ __align__(16) float s_b2[128], s_q2[128], s_r2[128];
    __shared__ float s_b1[32], s_q1[32], s_r1[32], s_b0[8], s_q0[8];
    __shared__ float s_asp[256], s_lpi[32];
    __shared__ float s_scal[12], s_Alh[4];

    int* cnt = (int*)ws + WS_CNT + (b * 16 + g) * 2;

    // ---- register prefetch: 8 leaf-lgb values (consumed only at d=5) ----
    const float ldc8 = ws[WS_LOGDEN + g * 8 + c8];
    float rL[8];
    {
        const int lbase = b * 5461 + 1365 + s * 256;
        int labq[8];
        #pragma unroll
        for (int it = 0; it < 2; ++it) {
            const int p = (it * 256 + t) >> 3;
            #pragma unroll
            for (int j = 0; j < 4; ++j) labq[it * 4 + j] = labels[lbase + 4 * p + j];
        }
        #pragma unroll
        for (int z = 0; z < 8; ++z)
            rL[z] = B[((size_t)(c8 * 8192) + labq[z]) * 16 + g];
    }

    s_asp[t] = ws[WS_ASP + g * 256 + t];
    if (t < 32) s_lpi[t] = ws[WS_LPI + g * 32 + t];
    {
        const float4* bsrc = (const float4*)(ws + WS_BLEAF + (size_t)g * 32768 + (size_t)s * 2048);
        ((float4*)s_blf)[t] = bsrc[t];
        ((float4*)s_blf)[t + 256] = bsrc[t + 256];
    }
    #pragma unroll
    for (int it = 0; it < 3; ++it) {              // node-lgb gather (once)
        const int q = it * 256 + t;
        if (q < 720) {
            const int nl = q >> 3, c = q & 7;
            const int lab = labels[b * 5461 + node_id(nl, s)];
            s_lgb[q] = B[((size_t)(c * 8192) + lab) * 16 + g] - ws[WS_LOGDEN + g * 8 + c];
        }
    }
    if (s == 0) {
        #pragma unroll
        for (int it = 0; it < 3; ++it) {
            const int idx = it * 256 + t;
            if (idx < 640) {
                const int nm = idx >> 3, c = idx & 7;
                const int lab = labels[b * 5461 + 5 + nm];
                s_lgbM[idx] = B[((size_t)(c * 8192) + lab) * 16 + g] - ws[WS_LOGDEN + g * 8 + c];
            }
        }
    }
    __syncthreads();

    float aspR[32];   // UP layout: [k*4+j] = A_SP[i=c8,k,j]
    #pragma unroll
    for (int k = 0; k < 8; ++k)
        #pragma unroll
        for (int j = 0; j < 4; ++j) aspR[k * 4 + j] = s_asp[(c8 * 8 + k) * 4 + j];

    // ---- up-sweep (own subtree), all state in LDS ----
    #pragma unroll
    for (int it = 0; it < 2; ++it) {              // L5: 64 nodes
        const int p = (it * 256 + t) >> 3;
        const float tt = up_tt(s_blf + p * 32, aspR);
        const float bu = tt * __expf(s_lgb[(26 + p) * 8 + c8]);
        float ssum = bu;
        ssum += __shfl_xor(ssum, 1); ssum += __shfl_xor(ssum, 2); ssum += __shfl_xor(ssum, 4);
        const float beta = bu / ssum;
        s_b5[p * 8 + c8] = beta; s_q5[p * 8 + c8] = beta / tt;
    }
    __syncthreads();
    if (t < 128) {                                // L4: 16
        const int p = t >> 3;
        const float tt = up_tt(s_b5 + p * 32, aspR);
        const float bu = tt * __expf(s_lgb[(10 + p) * 8 + c8]);
        float ssum = bu;
        ssum += __shfl_xor(ssum, 1); ssum += __shfl_xor(ssum, 2); ssum += __shfl_xor(ssum, 4);
        const float beta = bu / ssum;
        s_b4[p * 8 + c8] = beta; s_q4[p * 8 + c8] = beta / tt;
    }
    __syncthreads();
    if (t < 32) {                                 // L3: 4
        const int p = t >> 3;
        const float tt = up_tt(s_b4 + p * 32, aspR);
        const float bu = tt * __expf(s_lgb[(6 + p) * 8 + c8]);
        float ssum = bu;
        ssum += __shfl_xor(ssum, 1); ssum += __shfl_xor(ssum, 2); ssum += __shfl_xor(ssum, 4);
        const float beta = bu / ssum;
        s_b3o[p * 8 + c8] = beta; s_q3[p * 8 + c8] = beta / tt;
    }
    __syncthreads();

    // ---- exchange publish: RETURNING atomics (completion proven), then counter ----
    float* X = ws + WS_XCHG + (size_t)(b * 16 + g) * 768;
    float dummy = 0.f;
    if (t < 8) {
        const float tt = up_tt(s_b3o, aspR);
        const float bu = tt * __expf(s_lgb[5 * 8 + c8]);
        float ssum = bu;
        ssum += __shfl_xor(ssum, 1); ssum += __shfl_xor(ssum, 2); ssum += __shfl_xor(ssum, 4);
        const float beta = bu / ssum;
        dummy += atomicExch(&X[s * 8 + c8], beta);
        dummy += atomicExch(&X[128 + s * 8 + c8], beta / tt);
    }
    if (t < 32) dummy += atomicExch(&X[256 + s * 32 + t], s_b3o[t]);
    if (dummy == 1234.5678f) s_scal[11] = dummy;  // consume returns -> sc0 (returning) variant
    __syncthreads();                              // vmcnt drained: all RMWs performed
    if (t == 0) atomicAdd(&cnt[0], 1);

    // ---- consume: single-lane spin, then one atomic read per slot ----
    if (t == 0) {
        while (atomicAdd(&cnt[0], 0) < 16) __builtin_amdgcn_s_sleep(2);
    }
    __syncthreads();
    {
        const float v = atomicAdd(&X[t], 0.f);
        if (t < 128) s_b2[t] = v; else s_q2[t - 128] = v;
        if (s == 0) {
            s_b3a[t] = atomicAdd(&X[256 + t], 0.f);
            s_b3a[256 + t] = atomicAdd(&X[512 + t], 0.f);
        }
    }
    __syncthreads();

    // ---- middle up (replicated per subtree) ----
    if (t < 32) {                                 // L1
        const int p = t >> 3;
        const float tt = up_tt(s_b2 + p * 32, aspR);
        const float bu = tt * __expf(s_lgb[(1 + p) * 8 + c8]);
        float ssum = bu;
        ssum += __shfl_xor(ssum, 1); ssum += __shfl_xor(ssum, 2); ssum += __shfl_xor(ssum, 4);
        s_b1[p * 8 + c8] = bu / ssum;
        s_q1[p * 8 + c8] = (bu / ssum) / tt;
    }
    __syncthreads();
    if (t < 8) {                                  // L0
        const float tt = up_tt(s_b1, aspR);
        const float bu = tt * __expf(s_lgb[c8]);
        float ssum = bu;
        ssum += __shfl_xor(ssum, 1); ssum += __shfl_xor(ssum, 2); ssum += __shfl_xor(ssum, 4);
        s_b0[c8] = bu / ssum;
        s_q0[c8] = (bu / ssum) / tt;
    }
    __syncthreads();

    #pragma unroll
    for (int i = 0; i < 8; ++i)                   // DOWN layout: [i*4+j] = A_SP[i,k=c8,j]
        #pragma unroll
        for (int j = 0; j < 4; ++j) aspR[i * 4 + j] = s_asp[(i * 8 + c8) * 4 + j];

    float pB = 0.f, pPi = 0.f;
    float Sacc[32];
    #pragma unroll
    for (int z = 0; z < 32; z++) Sacc[z] = 0.f;

    // d=0
    if (t < 8) {
        float r8[8], u[4];
        #pragma unroll
        for (int i = 0; i < 8; i++) r8[i] = s_q0[i];
        down_u(r8, aspR, u);
        #pragma unroll
        for (int j = 0; j < 4; j++) s_r1[j * 8 + c8] = s_q1[j * 8 + c8] * u[j];
        if (s == 0) {
            pB += s_b0[c8] * s_lgb[c8];
            #pragma unroll
            for (int j = 0; j < 4; j++) {
                const float bc = s_b1[j * 8 + c8];
                pB += bc * u[j] * s_lgb[(1 + j) * 8 + c8];
                #pragma unroll
                for (int i = 0; i < 8; i++) Sacc[i * 4 + j] += r8[i] * bc;
            }
        }
    }
    __syncthreads();
    // d=1
    if (t < 32) {
        const int p = t >> 3;
        float r8[8], u[4];
        #pragma unroll
        for (int i = 0; i < 8; i++) r8[i] = s_r1[p * 8 + i];
        down_u(r8, aspR, u);
        #pragma unroll
        for (int j = 0; j < 4; j++) {
            const int ch = 4 * p + j;
            s_r2[ch * 8 + c8] = s_q2[ch * 8 + c8] * u[j];
            if (s == 0) {
                const float bc = s_b2[ch * 8 + c8];
                pB += bc * u[j] * s_lgbM[ch * 8 + c8];
                #pragma unroll
                for (int i = 0; i < 8; i++) Sacc[i * 4 + j] += r8[i] * bc;
            }
        }
    }
    __syncthreads();
    // d=2
    if (t < 128) {
        const int p = t >> 3;
        float r8[8], u[4];
        #pragma unroll
        for (int i = 0; i < 8; i++) r8[i] = s_r2[p * 8 + i];
        down_u(r8, aspR, u);
        #pragma unroll
        for (int j = 0; j < 4; j++) {
            const int ch = 4 * p + j;
            if (p == s) s_r3[j * 8 + c8] = s_q3[j * 8 + c8] * u[j];
            if (s == 0) {
                const float bc = s_b3a[ch * 8 + c8];
                pB += bc * u[j] * s_lgbM[(16 + ch) * 8 + c8];
                #pragma unroll
                for (int i = 0; i < 8; i++) Sacc[i * 4 + j] += r8[i] * bc;
            }
        }
    }
    __syncthreads();
    // d=3
    if (t < 32) {
        const int p = t >> 3;
        float r8[8], u[4];
        #pragma unroll
        for (int i = 0; i < 8; i++) r8[i] = s_r3[p * 8 + i];
        down_u(r8, aspR, u);
        #pragma unroll
        for (int j = 0; j < 4; j++) {
            const int ch = 4 * p + j;
            const float bc = s_b4[ch * 8 + c8];
            pB += bc * u[j] * s_lgb[(10 + ch) * 8 + c8];
            s_r4[ch * 8 + c8] = s_q4[ch * 8 + c8] * u[j];
            #pragma unroll
            for (int i = 0; i < 8; i++) Sacc[i * 4 + j] += r8[i] * bc;
        }
    }
    __syncthreads();
    // d=4
    if (t < 128) {
        const int p = t >> 3;
        float r8[8], u[4];
        #pragma unroll
        for (int i = 0; i < 8; i++) r8[i] = s_r4[p * 8 + i];
        down_u(r8, aspR, u);
        #pragma unroll
        for (int j = 0; j < 4; j++) {
            const int ch = 4 * p + j;
            const float bc = s_b5[ch * 8 + c8];
            pB += bc * u[j] * s_lgb[(26 + ch) * 8 + c8];
            s_r5[ch * 8 + c8] = s_q5[ch * 8 + c8] * u[j];
            #pragma unroll
            for (int i = 0; i < 8; i++) Sacc[i * 4 + j] += r8[i] * bc;
        }
    }
    __syncthreads();
    // d=5 (leaves): leaf-lgb from registers
    #pragma unroll
    for (int it = 0; it < 2; ++it) {
        const int p = (it * 256 + t) >> 3;
        float r8[8], u[4];
        #pragma unroll
        for (int i = 0; i < 8; i++) r8[i] = s_r5[p * 8 + i];
        down_u(r8, aspR, u);
        #pragma unroll
        for (int j = 0; j < 4; j++) {
            const int q = 4 * p + j;
            const float bc = s_blf[q * 8 + c8];
            const float e6 = bc * u[j];
            pB += e6 * (rL[it * 4 + j] - ldc8);
            pPi += e6 * s_lpi[c8 * 4 + j];
            #pragma unroll
            for (int i = 0; i < 8; i++) Sacc[i * 4 + j] += r8[i] * bc;
        }
    }

    // ---- epilogue: reduce, publish via returning atomics, bump finalize counter ----
    #pragma unroll
    for (int z = 0; z < 32; z++) {
        float v = Sacc[z];
        v += __shfl_xor(v, 8);
        v += __shfl_xor(v, 16);
        v += __shfl_xor(v, 32);
        Sacc[z] = v;
    }
    #pragma unroll
    for (int m = 1; m < 64; m <<= 1) { pB += __shfl_xor(pB, m); pPi += __shfl_xor(pPi, m); }
    float* s_stage = s_blf;                       // alias: blf dead after d5
    __syncthreads();
    if (lane < 8) {
        #pragma unroll
        for (int z = 0; z < 32; z++)
            s_stage[wv * 256 + ((z >> 2) * 8 + lane) * 4 + (z & 3)] = Sacc[z];
    }
    if (lane == 0) { s_scal[wv] = pB; s_scal[4 + wv] = pPi; }
    __syncthreads();
    {
        const float TS = s_stage[t] + s_stage[256 + t] + s_stage[512 + t] + s_stage[768 + t];
        float* SgW = ws + WS_SG + ((size_t)(b * 16 + g) * 16 + s) * 256;
        float d2 = atomicExch(&SgW[t], TS);
        float* PgW = ws + WS_PG + ((size_t)(b * 16 + g) * 16 + s) * 2;
        if (t == 0) d2 += atomicExch(&PgW[0], s_scal[0] + s_scal[1] + s_scal[2] + s_scal[3]);
        if (t == 1) d2 += atomicExch(&PgW[1], s_scal[4] + s_scal[5] + s_scal[6] + s_scal[7]);
        if (d2 == 1234.5678f) s_scal[11] = d2;    // consume returns -> sc0
    }
    __syncthreads();                              // all publish RMWs performed
    if (t == 0) atomicAdd(&cnt[1], 1);

    // ---- finalize: block s==15 waits on counter, then single reads ----
    if (s == 15) {
        if (t == 0) {
            while (atomicAdd(&cnt[1], 0) < 16) __builtin_amdgcn_s_sleep(2);
        }
        if (t < 4) s_Alh[t] = 0.f;
        __syncthreads();
        float Ssum = 0.f;
        float* SgB = ws + WS_SG + (size_t)(b * 16 + g) * 4096;
        #pragma unroll
        for (int sp = 0; sp < 16; ++sp)
            Ssum += atomicAdd(&SgB[sp * 256 + t], 0.f);
        if (t < 2) {
            float* PgB = ws + WS_PG + (size_t)(b * 16 + g) * 32;
            float tot = 0.f;
            #pragma unroll
            for (int sp = 0; sp < 16; ++sp)
                tot += atomicAdd(&PgB[sp * 2 + t], 0.f);
            s_scal[8 + t] = tot;
        }
        __syncthreads();
        const float val = s_asp[t] * Ssum;
        atomicAdd(&s_Alh[t & 3], val * ws[WS_LOGA + g * 256 + t]);
        __syncthreads();
        out[(size_t)b * 4096 + t * 16 + g] =
            -(s_Alh[t & 3] + s_scal[8] + s_scal[9] + val * ws[WS_LSP + g * 4 + (t & 3)]);
    }
}

extern "C" void kernel_launch(void* const* d_in, const int* in_sizes, int n_in,
                              void* d_out, int out_size, void* d_ws, size_t ws_size,
                              hipStream_t stream) {
    (void)in_sizes; (void)n_in; (void)out_size; (void)ws_size;
    const int* labels = (const int*)d_in[0];
    const float* A  = (const float*)d_in[1];
    const float* B  = (const float*)d_in[2];
    const float* Pi = (const float*)d_in[3];
    const float* SP = (const float*)d_in[4];
    float* ws = (float*)d_ws;
    float* out = (float*)d_out;

    hipLaunchKernelGGL(k_pre,  dim3(1024), dim3(256), 0, stream, B, ws);
    hipLaunchKernelGGL(k_mid,  dim3(272),  dim3(256), 0, stream, A, B, Pi, SP, ws);
    hipLaunchKernelGGL(k_tree, dim3(1024), dim3(256), 0, stream, labels, B, ws, out);
}

// Round 11
// 123.197 us; speedup vs baseline: 1.0172x; 1.0172x over previous
//
#include <hip/hip_runtime.h>

// C=8, L=4, M=8192, NGEN=16, DEPTH=6, BATCH=4, N=5461
// Level starts: L0:0 L1:1 L2:5 L3:21 L4:85 L5:341 leaves:1365
// Subtree s (0..15) rooted at L2 node 5+s.

// ---- workspace layout (4B units) ----
#define WS_PART   0        // 32768
#define WS_LOGDEN 32768    // 128  [g*8+c]
#define WS_ASP    32896    // 4096 [g*256 + (i*8+k)*4+j]
#define WS_LOGA   36992    // 4096
#define WS_LPI    41088    // 512
#define WS_LSP    41600    // 64
#define WS_BLEAF  41664    // 524288 [g*32768 + p*8 + c]
#define WS_LGB    565952   // 2796032 [b][g][node*8+c], stride 43688 per (b,g)
#define WS_XCHG   3361984  // 64*768 per (b,g): [B2 0..128 | Q2 128..256 | B3 256..768]
#define WS_SG     3411136  // 64*16*256  per (b,g): [s][t]
#define WS_PG     3673280  // 64*16*2    per (b,g): [s][{pB,pPi}]
#define SENTINEL  0xAAAAAAAAu

__device__ __forceinline__ int node_id(int nl, int s) {
    if (nl == 0) return 0;
    if (nl < 5)  return nl;
    if (nl == 5) return 5 + s;
    if (nl < 10) return 21 + 4 * s + (nl - 6);
    if (nl < 26) return 85 + 16 * s + (nl - 10);
    return 341 + 64 * s + (nl - 26);
}

__device__ __forceinline__ float up_tt(const float* bp, const float* aspU) {
    float tt = 0.f;
    #pragma unroll
    for (int j = 0; j < 4; j++) {
        float4 lo = *(const float4*)(bp + j * 8);
        float4 hi = *(const float4*)(bp + j * 8 + 4);
        tt += aspU[0 + j] * lo.x + aspU[4 + j] * lo.y + aspU[8 + j] * lo.z + aspU[12 + j] * lo.w
            + aspU[16 + j] * hi.x + aspU[20 + j] * hi.y + aspU[24 + j] * hi.z + aspU[28 + j] * hi.w;
    }
    return tt;
}

__device__ __forceinline__ void down_u(const float* r8, const float* aspD, float* u) {
    u[0] = u[1] = u[2] = u[3] = 0.f;
    #pragma unroll
    for (int i = 0; i < 8; i++) {
        u[0] += aspD[i * 4 + 0] * r8[i];
        u[1] += aspD[i * 4 + 1] * r8[i];
        u[2] += aspD[i * 4 + 2] * r8[i];
        u[3] += aspD[i * 4 + 3] * r8[i];
    }
}

// spin until slot holds a strictly-positive value (sentinel is negative)
__device__ __forceinline__ float spin_pos(float* p) {
    float v = atomicAdd(p, 0.f);
    while (!(v > 0.f)) { __builtin_amdgcn_s_sleep(1); v = atomicAdd(p, 0.f); }
    return v;
}
// spin until slot differs from the sentinel bit pattern
__device__ __forceinline__ float spin_sent(float* p) {
    float v = atomicAdd(p, 0.f);
    while (__float_as_uint(v) == SENTINEL) { __builtin_amdgcn_s_sleep(1); v = atomicAdd(p, 0.f); }
    return v;
}

// ---------------- K1: B logsumexp partials + sentinel-init channels ----------------
__global__ __launch_bounds__(256) void k_pre(const float* __restrict__ B, float* __restrict__ ws) {
    const int x = blockIdx.x, t = threadIdx.x;
    const int lane = t & 63, wv = t >> 6;
    __shared__ float s_stage[128];
    if (x < 64) {
        unsigned* wu = (unsigned*)ws;
        for (int i = t; i < 4096; i += 256) wu[WS_SG + (size_t)x * 4096 + i] = SENTINEL;
        if (t < 32) wu[WS_PG + x * 32 + t] = SENTINEL;
        for (int i = t; i < 768; i += 256) wu[WS_XCHG + (size_t)x * 768 + i] = SENTINEL;
    }
    const int cA = x >> 7, chunk = x & 127;
    const float* Bp = B + ((size_t)(cA * 8192) + chunk * 64) * 16;
    float mx = -3.4e38f, sE = 0.f;
    #pragma unroll
    for (int pass = 0; pass < 4; ++pass) {
        const float v = Bp[pass * 256 + t];
        const float nm = fmaxf(mx, v);
        sE = sE * __expf(mx - nm) + __expf(v - nm);
        mx = nm;
    }
    #pragma unroll
    for (int mk = 16; mk <= 32; mk <<= 1) {
        const float om = __shfl_xor(mx, mk), os = __shfl_xor(sE, mk);
        const float nm = fmaxf(mx, om);
        sE = sE * __expf(mx - nm) + os * __expf(om - nm);
        mx = nm;
    }
    if (lane < 16) { s_stage[(wv * 16 + lane) * 2] = mx; s_stage[(wv * 16 + lane) * 2 + 1] = sE; }
    __syncthreads();
    if (t < 16) {
        float M = s_stage[t * 2], S = s_stage[t * 2 + 1];
        #pragma unroll
        for (int w = 1; w < 4; ++w) {
            const float om = s_stage[(w * 16 + t) * 2], os = s_stage[(w * 16 + t) * 2 + 1];
            const float nm = fmaxf(M, om);
            S = S * __expf(M - nm) + os * __expf(om - nm);
            M = nm;
        }
        ws[WS_PART + ((t * 8 + cA) * 128 + chunk) * 2]     = M;
        ws[WS_PART + ((t * 8 + cA) * 128 + chunk) * 2 + 1] = S;
    }
}

// ---------------- K2: bleaf (0..255) + params (256..271) + LGB gather (272..954) ----------------
__global__ __launch_bounds__(256) void k_mid(const int* __restrict__ labels,
                                             const float* __restrict__ A,
                                             const float* __restrict__ B,
                                             const float* __restrict__ Pi,
                                             const float* __restrict__ SP,
                                             float* __restrict__ ws) {
    const int x = blockIdx.x, t = threadIdx.x;
    if (x >= 256 && x < 272) {
        // ---- params for g = x-256 ----
        const int g = x - 256;
        __shared__ float s_st[256], s_expA[256], s_spe[4], s_pie[32];
        if (t < 128) {
            const int c2 = t >> 4, part = t & 15;
            const float* pp = ws + WS_PART + (size_t)(((g * 8 + c2) * 128 + part * 8) * 2);
            float M = -3.4e38f, S = 0.f;
            #pragma unroll
            for (int q = 0; q < 8; ++q) {
                const float om = pp[q * 2], os = pp[q * 2 + 1];
                const float nm = fmaxf(M, om);
                S = S * __expf(M - nm) + os * __expf(om - nm);
                M = nm;
            }
            s_st[t * 2] = M; s_st[t * 2 + 1] = S;
        }
        const float Av = A[t * 16 + g];
        s_expA[t] = __expf(Av);
        if (t < 4) s_spe[t] = __expf(SP[t * 16 + g]);
        if (t >= 32 && t < 64) s_pie[t - 32] = __expf(Pi[(t - 32) * 16 + g]);
        __syncthreads();
        if (t < 8) {
            float M = s_st[(t * 16) * 2], S = s_st[(t * 16) * 2 + 1];
            #pragma unroll
            for (int q = 1; q < 16; ++q) {
                const float om = s_st[(t * 16 + q) * 2], os = s_st[(t * 16 + q) * 2 + 1];
                const float nm = fmaxf(M, om);
                S = S * __expf(M - nm) + os * __expf(om - nm);
                M = nm;
            }
            ws[WS_LOGDEN + g * 8 + t] = M + __logf(S);
        }
        {
            const int kk = (t >> 2) & 7, jj = t & 3;
            float sumA = 0.f;
            #pragma unroll
            for (int i = 0; i < 8; ++i) sumA += s_expA[(i * 8 + kk) * 4 + jj];
            const float sps = s_spe[0] + s_spe[1] + s_spe[2] + s_spe[3];
            ws[WS_ASP + g * 256 + t]  = s_expA[t] / sumA * (s_spe[jj] / sps);
            ws[WS_LOGA + g * 256 + t] = Av - __logf(sumA);
            if (t < 4) ws[WS_LSP + g * 4 + t] = SP[t * 16 + g] - __logf(sps);
            if (t < 32) {
                float ps = 0.f;
                #pragma unroll
                for (int i2 = 0; i2 < 8; ++i2) ps += s_pie[i2 * 4 + (t & 3)];
                ws[WS_LPI + g * 32 + t] = Pi[t * 16 + g] - __logf(ps);
            }
        }
    } else {
        // both bleaf and gather branches need logden for all (c,g)
        __shared__ float s_ld[128];
        {
            const int pair = t >> 1, half = t & 1;
            const int c = pair >> 4, gg = pair & 15;
            const float* pp = ws + WS_PART + (size_t)(((gg * 8 + c) * 128 + half * 64) * 2);
            float M = -3.4e38f, S = 0.f;
            for (int q = 0; q < 64; ++q) {
                const float om = pp[q * 2], os = pp[q * 2 + 1];
                const float nm = fmaxf(M, om);
                S = S * __expf(M - nm) + os * __expf(om - nm);
                M = nm;
            }
            const float om = __shfl_xor(M, 1), os = __shfl_xor(S, 1);
            const float nm = fmaxf(M, om);
            S = S * __expf(M - nm) + os * __expf(om - nm);
            M = nm;
            if (half == 0) s_ld[c * 16 + gg] = M + __logf(S);
        }
        if (x < 256) {
            // ---- bleaf ----
            __shared__ float s_pie[512], s_smpi[512];
            s_pie[t] = __expf(Pi[t]);
            s_pie[256 + t] = __expf(Pi[256 + t]);
            __syncthreads();
            #pragma unroll
            for (int h = 0; h < 2; ++h) {
                const int idx = h * 256 + t;
                const int jg = idx & 63;
                float ps = 0.f;
                #pragma unroll
                for (int c2 = 0; c2 < 8; ++c2) ps += s_pie[c2 * 64 + jg];
                s_smpi[idx] = s_pie[idx] / ps;
            }
            __syncthreads();
            const int id = x * 256 + t;
            const int g = id & 15, p = id >> 4;
            const int pos = p & 3;
            float vals[8], ssum = 0.f;
            #pragma unroll
            for (int c = 0; c < 8; ++c) {
                const float v = s_smpi[(c * 4 + pos) * 16 + g] *
                    __expf(B[((size_t)(c * 8192) + 1365 + p) * 16 + g] - s_ld[c * 16 + g]);
                vals[c] = v; ssum += v;
            }
            const float inv = 1.f / ssum;
            float* o = ws + WS_BLEAF + (size_t)g * 32768 + (size_t)p * 8;
            *(float4*)o       = make_float4(vals[0] * inv, vals[1] * inv, vals[2] * inv, vals[3] * inv);
            *(float4*)(o + 4) = make_float4(vals[4] * inv, vals[5] * inv, vals[6] * inv, vals[7] * inv);
        } else {
            // ---- LGB gather: thread per (b,node,c); writes coalesce per wave per g ----
            __syncthreads();
            const int item = (x - 272) * 256 + t;   // 174752 = 4b * 5461node * 8c
            if (item < 174752) {
                const int b = item / 43688;
                const int rem = item - b * 43688;
                const int node = rem >> 3, c = rem & 7;
                const int lv = labels[b * 5461 + node];
                const float* bp = B + ((size_t)(c * 8192) + lv) * 16;
                const float4 q0 = *(const float4*)bp;
                const float4 q1 = *(const float4*)(bp + 4);
                const float4 q2 = *(const float4*)(bp + 8);
                const float4 q3 = *(const float4*)(bp + 12);
                const float vg[16] = {q0.x,q0.y,q0.z,q0.w, q1.x,q1.y,q1.z,q1.w,
                                      q2.x,q2.y,q2.z,q2.w, q3.x,q3.y,q3.z,q3.w};
                float* dst = ws + WS_LGB + (size_t)b * (16 * 43688) + (size_t)node * 8 + c;
                #pragma unroll
                for (int g = 0; g < 16; ++g)
                    dst[(size_t)g * 43688] = vg[g] - s_ld[c * 16 + g];
            }
        }
    }
}

// ---------------- K3: fused up + data-ready exchange + down + finalize (all dense loads) ----------------
__global__ __launch_bounds__(256, 4) void k_tree(float* __restrict__ ws,
                                                 float* __restrict__ out) {
    const int x = blockIdx.x, t = threadIdx.x;
    const int s = x & 15, g = (x >> 4) & 15, b = x >> 8;
    const int c8 = t & 7, lane = t & 63, wv = t >> 6;

    __shared__ __align__(16) float s_blf[2048];   // aliased as epilogue stage after d5
    __shared__ __align__(16) float s_lgb[720];
    __shared__ __align__(16) float s_lgbM[640];   // s==0 only: nodes 5..84 (contiguous in LGB)
    __shared__ __align__(16) float s_b5[512], s_q5[512], s_r5[512];
    __shared__ __align__(16) float s_b4[128], s_q4[128], s_r4[128];
    __shared__ __align__(16) float s_b3o[32], s_b3a[512], s_q3[32], s_r3[32];
    __shared__ __align__(16) float s_b2[128], s_q2[128], s_r2[128];
    __shared__ float s_b1[32], s_q1[32], s_r1[32], s_b0[8], s_q0[8];
    __shared__ float s_asp[256], s_lpi[32];
    __shared__ float s_scal[12], s_Alh[4];

    const float* lgbP = ws + WS_LGB + (size_t)(b * 16 + g) * 43688;

    // ---- register prefetch: 8 leaf-lgb values, DENSE from LGB leaf segment ----
    float rL[8];
    #pragma unroll
    for (int it = 0; it < 2; ++it) {
        const int p = (it * 256 + t) >> 3;
        #pragma unroll
        for (int j = 0; j < 4; ++j)
            rL[it * 4 + j] = lgbP[(1365 + s * 256 + 4 * p + j) * 8 + c8];
    }

    s_asp[t] = ws[WS_ASP + g * 256 + t];
    if (t < 32) s_lpi[t] = ws[WS_LPI + g * 32 + t];
    {
        const float4* bsrc = (const float4*)(ws + WS_BLEAF + (size_t)g * 32768 + (size_t)s * 2048);
        ((float4*)s_blf)[t] = bsrc[t];
        ((float4*)s_blf)[t + 256] = bsrc[t + 256];
    }
    #pragma unroll
    for (int it = 0; it < 3; ++it) {              // node-lgb: dense segment loads
        const int q = it * 256 + t;
        if (q < 720) {
            const int nl = q >> 3, c = q & 7;
            s_lgb[q] = lgbP[node_id(nl, s) * 8 + c];
        }
    }
    if (s == 0) {                                 // nodes 5..84: one contiguous run
        #pragma unroll
        for (int it = 0; it < 3; ++it) {
            const int idx = it * 256 + t;
            if (idx < 640) s_lgbM[idx] = lgbP[40 + idx];
        }
    }
    __syncthreads();

    float aspR[32];   // UP layout: [k*4+j] = A_SP[i=c8,k,j]
    #pragma unroll
    for (int k = 0; k < 8; ++k)
        #pragma unroll
        for (int j = 0; j < 4; ++j) aspR[k * 4 + j] = s_asp[(c8 * 8 + k) * 4 + j];

    // ---- up-sweep (own subtree), all state in LDS ----
    #pragma unroll
    for (int it = 0; it < 2; ++it) {              // L5: 64 nodes
        const int p = (it * 256 + t) >> 3;
        const float tt = up_tt(s_blf + p * 32, aspR);
        const float bu = tt * __expf(s_lgb[(26 + p) * 8 + c8]);
        float ssum = bu;
        ssum += __shfl_xor(ssum, 1); ssum += __shfl_xor(ssum, 2); ssum += __shfl_xor(ssum, 4);
        const float beta = bu / ssum;
        s_b5[p * 8 + c8] = beta; s_q5[p * 8 + c8] = beta / tt;
    }
    __syncthreads();
    if (t < 128) {                                // L4: 16
        const int p = t >> 3;
        const float tt = up_tt(s_b5 + p * 32, aspR);
        const float bu = tt * __expf(s_lgb[(10 + p) * 8 + c8]);
        float ssum = bu;
        ssum += __shfl_xor(ssum, 1); ssum += __shfl_xor(ssum, 2); ssum += __shfl_xor(ssum, 4);
        const float beta = bu / ssum;
        s_b4[p * 8 + c8] = beta; s_q4[p * 8 + c8] = beta / tt;
    }
    __syncthreads();
    if (t < 32) {                                 // L3: 4
        const int p = t >> 3;
        const float tt = up_tt(s_b4 + p * 32, aspR);
        const float bu = tt * __expf(s_lgb[(6 + p) * 8 + c8]);
        float ssum = bu;
        ssum += __shfl_xor(ssum, 1); ssum += __shfl_xor(ssum, 2); ssum += __shfl_xor(ssum, 4);
        const float beta = bu / ssum;
        s_b3o[p * 8 + c8] = beta; s_q3[p * 8 + c8] = beta / tt;
    }
    __syncthreads();
    float* X = ws + WS_XCHG + (size_t)(b * 16 + g) * 768;
    if (t < 8) {                                  // L2 -> exchange (value IS the ready flag)
        const float tt = up_tt(s_b3o, aspR);
        const float bu = tt * __expf(s_lgb[5 * 8 + c8]);
        float ssum = bu;
        ssum += __shfl_xor(ssum, 1); ssum += __shfl_xor(ssum, 2); ssum += __shfl_xor(ssum, 4);
        const float beta = bu / ssum;
        atomicExch(&X[s * 8 + c8], beta);
        atomicExch(&X[128 + s * 8 + c8], beta / tt);
    }
    if (t < 32) atomicExch(&X[256 + s * 32 + t], s_b3o[t]);

    // ---- data-ready consume: spin per element ----
    {
        const float v = spin_pos(&X[t]);
        if (t < 128) s_b2[t] = v; else s_q2[t - 128] = v;
        if (s == 0) {
            s_b3a[t] = spin_pos(&X[256 + t]);
            s_b3a[256 + t] = spin_pos(&X[512 + t]);
        }
    }
    __syncthreads();

    // ---- middle up (replicated per subtree) ----
    if (t < 32) {                                 // L1
        const int p = t >> 3;
        const float tt = up_tt(s_b2 + p * 32, aspR);
        const float bu = tt * __expf(s_lgb[(1 + p) * 8 + c8]);
        float ssum = bu;
        ssum += __shfl_xor(ssum, 1); ssum += __shfl_xor(ssum, 2); ssum += __shfl_xor(ssum, 4);
        s_b1[p * 8 + c8] = bu / ssum;
        s_q1[p * 8 + c8] = (bu / ssum) / tt;
    }
    __syncthreads();
    if (t < 8) {                                  // L0
        const float tt = up_tt(s_b1, aspR);
        const float bu = tt * __expf(s_lgb[c8]);
        float ssum = bu;
        ssum += __shfl_xor(ssum, 1); ssum += __shfl_xor(ssum, 2); ssum += __shfl_xor(ssum, 4);
        s_b0[c8] = bu / ssum;
        s_q0[c8] = (bu / ssum) / tt;
    }
    __syncthreads();

    #pragma unroll
    for (int i = 0; i < 8; ++i)                   // DOWN layout: [i*4+j] = A_SP[i,k=c8,j]
        #pragma unroll
        for (int j = 0; j < 4; ++j) aspR[i * 4 + j] = s_asp[(i * 8 + c8) * 4 + j];

    float pB = 0.f, pPi = 0.f;
    float Sacc[32];
    #pragma unroll
    for (int z = 0; z < 32; z++) Sacc[z] = 0.f;

    // d=0
    if (t < 8) {
        float r8[8], u[4];
        #pragma unroll
        for (int i = 0; i < 8; i++) r8[i] = s_q0[i];
        down_u(r8, aspR, u);
        #pragma unroll
        for (int j = 0; j < 4; j++) s_r1[j * 8 + c8] = s_q1[j * 8 + c8] * u[j];
        if (s == 0) {
            pB += s_b0[c8] * s_lgb[c8];
            #pragma unroll
            for (int j = 0; j < 4; j++) {
                const float bc = s_b1[j * 8 + c8];
                pB += bc * u[j] * s_lgb[(1 + j) * 8 + c8];
                #pragma unroll
                for (int i = 0; i < 8; i++) Sacc[i * 4 + j] += r8[i] * bc;
            }
        }
    }
    __syncthreads();
    // d=1
    if (t < 32) {
        const int p = t >> 3;
        float r8[8], u[4];
        #pragma unroll
        for (int i = 0; i < 8; i++) r8[i] = s_r1[p * 8 + i];
        down_u(r8, aspR, u);
        #pragma unroll
        for (int j = 0; j < 4; j++) {
            const int ch = 4 * p + j;
            s_r2[ch * 8 + c8] = s_q2[ch * 8 + c8] * u[j];
            if (s == 0) {
                const float bc = s_b2[ch * 8 + c8];
                pB += bc * u[j] * s_lgbM[ch * 8 + c8];
                #pragma unroll
                for (int i = 0; i < 8; i++) Sacc[i * 4 + j] += r8[i] * bc;
            }
        }
    }
    __syncthreads();
    // d=2
    if (t < 128) {
        const int p = t >> 3;
        float r8[8], u[4];
        #pragma unroll
        for (int i = 0; i < 8; i++) r8[i] = s_r2[p * 8 + i];
        down_u(r8, aspR, u);
        #pragma unroll
        for (int j = 0; j < 4; j++) {
            const int ch = 4 * p + j;
            if (p == s) s_r3[j * 8 + c8] = s_q3[j * 8 + c8] * u[j];
            if (s == 0) {
                const float bc = s_b3a[ch * 8 + c8];
                pB += bc * u[j] * s_lgbM[(16 + ch) * 8 + c8];
                #pragma unroll
                for (int i = 0; i < 8; i++) Sacc[i * 4 + j] += r8[i] * bc;
            }
        }
    }
    __syncthreads();
    // d=3
    if (t < 32) {
        const int p = t >> 3;
        float r8[8], u[4];
        #pragma unroll
        for (int i = 0; i < 8; i++) r8[i] = s_r3[p * 8 + i];
        down_u(r8, aspR, u);
        #pragma unroll
        for (int j = 0; j < 4; j++) {
            const int ch = 4 * p + j;
            const float bc = s_b4[ch * 8 + c8];
            pB += bc * u[j] * s_lgb[(10 + ch) * 8 + c8];
            s_r4[ch * 8 + c8] = s_q4[ch * 8 + c8] * u[j];
            #pragma unroll
            for (int i = 0; i < 8; i++) Sacc[i * 4 + j] += r8[i] * bc;
        }
    }
    __syncthreads();
    // d=4
    if (t < 128) {
        const int p = t >> 3;
        float r8[8], u[4];
        #pragma unroll
        for (int i = 0; i < 8; i++) r8[i] = s_r4[p * 8 + i];
        down_u(r8, aspR, u);
        #pragma unroll
        for (int j = 0; j < 4; j++) {
            const int ch = 4 * p + j;
            const float bc = s_b5[ch * 8 + c8];
            pB += bc * u[j] * s_lgb[(26 + ch) * 8 + c8];
            s_r5[ch * 8 + c8] = s_q5[ch * 8 + c8] * u[j];
            #pragma unroll
            for (int i = 0; i < 8; i++) Sacc[i * 4 + j] += r8[i] * bc;
        }
    }
    __syncthreads();
    // d=5 (leaves): leaf-lgb from registers (already logden-subtracted)
    #pragma unroll
    for (int it = 0; it < 2; ++it) {
        const int p = (it * 256 + t) >> 3;
        float r8[8], u[4];
        #pragma unroll
        for (int i = 0; i < 8; i++) r8[i] = s_r5[p * 8 + i];
        down_u(r8, aspR, u);
        #pragma unroll
        for (int j = 0; j < 4; j++) {
            const int q = 4 * p + j;
            const float bc = s_blf[q * 8 + c8];
            const float e6 = bc * u[j];
            pB += e6 * rL[it * 4 + j];
            pPi += e6 * s_lpi[c8 * 4 + j];
            #pragma unroll
            for (int i = 0; i < 8; i++) Sacc[i * 4 + j] += r8[i] * bc;
        }
    }

    // ---- epilogue: reduce, publish per-s slots (value == ready flag) ----
    #pragma unroll
    for (int z = 0; z < 32; z++) {
        float v = Sacc[z];
        v += __shfl_xor(v, 8);
        v += __shfl_xor(v, 16);
        v += __shfl_xor(v, 32);
        Sacc[z] = v;
    }
    #pragma unroll
    for (int m = 1; m < 64; m <<= 1) { pB += __shfl_xor(pB, m); pPi += __shfl_xor(pPi, m); }
    float* s_stage = s_blf;                       // alias: blf dead after d5
    __syncthreads();
    if (lane < 8) {
        #pragma unroll
        for (int z = 0; z < 32; z++)
            s_stage[wv * 256 + ((z >> 2) * 8 + lane) * 4 + (z & 3)] = Sacc[z];
    }
    if (lane == 0) { s_scal[wv] = pB; s_scal[4 + wv] = pPi; }
    __syncthreads();
    {
        const float TS = s_stage[t] + s_stage[256 + t] + s_stage[512 + t] + s_stage[768 + t];
        float* SgW = ws + WS_SG + ((size_t)(b * 16 + g) * 16 + s) * 256;
        atomicExch(&SgW[t], TS);                  // TS strictly > 0
        float* PgW = ws + WS_PG + ((size_t)(b * 16 + g) * 16 + s) * 2;
        if (t == 0) atomicExch(&PgW[0], s_scal[0] + s_scal[1] + s_scal[2] + s_scal[3]);
        if (t == 1) atomicExch(&PgW[1], s_scal[4] + s_scal[5] + s_scal[6] + s_scal[7]);
    }

    // ---- finalize: block s==15 spin-reads all 16 per-s slots ----
    if (s == 15) {
        if (t < 4) s_Alh[t] = 0.f;
        float Ssum = 0.f;
        float* SgB = ws + WS_SG + (size_t)(b * 16 + g) * 4096;
        #pragma unroll
        for (int sp = 0; sp < 16; ++sp)
            Ssum += spin_pos(&SgB[sp * 256 + t]);
        if (t < 2) {
            float* PgB = ws + WS_PG + (size_t)(b * 16 + g) * 32;
            float tot = 0.f;
            #pragma unroll
            for (int sp = 0; sp < 16; ++sp)
                tot += spin_sent(&PgB[sp * 2 + t]);
            s_scal[8 + t] = tot;
        }
        __syncthreads();
        const float val = s_asp[t] * Ssum;
        atomicAdd(&s_Alh[t & 3], val * ws[WS_LOGA + g * 256 + t]);
        __syncthreads();
        out[(size_t)b * 4096 + t * 16 + g] =
            -(s_Alh[t & 3] + s_scal[8] + s_scal[9] + val * ws[WS_LSP + g * 4 + (t & 3)]);
    }
}

extern "C" void kernel_launch(void* const* d_in, const int* in_sizes, int n_in,
                              void* d_out, int out_size, void* d_ws, size_t ws_size,
                              hipStream_t stream) {
    (void)in_sizes; (void)n_in; (void)out_size; (void)ws_size;
    const int* labels = (const int*)d_in[0];
    const float* A  = (const float*)d_in[1];
    const float* B  = (const float*)d_in[2];
    const float* Pi = (const float*)d_in[3];
    const float* SP = (const float*)d_in[4];
    float* ws = (float*)d_ws;
    float* out = (float*)d_out;

    hipLaunchKernelGGL(k_pre,  dim3(1024), dim3(256), 0, stream, B, ws);
    hipLaunchKernelGGL(k_mid,  dim3(955),  dim3(256), 0, stream, labels, A, B, Pi, SP, ws);
    hipLaunchKernelGGL(k_tree, dim3(1024), dim3(256), 0, stream, ws, out);
}

// Round 12
// 119.287 us; speedup vs baseline: 1.0505x; 1.0328x over previous
//
#include <hip/hip_runtime.h>

// C=8, L=4, M=8192, NGEN=16, DEPTH=6, BATCH=4, N=5461
// Level starts: L0:0 L1:1 L2:5 L3:21 L4:85 L5:341 leaves:1365
// Subtree s (0..15) rooted at L2 node 5+s.

// ---- workspace layout (4B units) ----
#define WS_PART   0        // 32768
#define WS_LOGDEN 32768    // 128  [g*8+c]
#define WS_ASP    32896    // 4096 [g*256 + (i*8+k)*4+j]
#define WS_LOGA   36992    // 4096
#define WS_LPI    41088    // 512
#define WS_LSP    41600    // 64
#define WS_BLEAF  41664    // 524288 [g*32768 + p*8 + c]
#define WS_LGB    565952   // 698880 = 64*10920: [b][g][node*8+c], INTERNAL nodes only
#define WS_XCHG   1264832  // 64*768 per (b,g): [B2 0..128 | Q2 128..256 | B3 256..768]
#define WS_SG     1313984  // 64*16*256  per (b,g): [s][t]
#define WS_PG     1576128  // 64*16*2    per (b,g): [s][{pB,pPi}]
#define SENTINEL  0xAAAAAAAAu

__device__ __forceinline__ int node_id(int nl, int s) {
    if (nl == 0) return 0;
    if (nl < 5)  return nl;
    if (nl == 5) return 5 + s;
    if (nl < 10) return 21 + 4 * s + (nl - 6);
    if (nl < 26) return 85 + 16 * s + (nl - 10);
    return 341 + 64 * s + (nl - 26);
}

__device__ __forceinline__ float up_tt(const float* bp, const float* aspU) {
    float tt = 0.f;
    #pragma unroll
    for (int j = 0; j < 4; j++) {
        float4 lo = *(const float4*)(bp + j * 8);
        float4 hi = *(const float4*)(bp + j * 8 + 4);
        tt += aspU[0 + j] * lo.x + aspU[4 + j] * lo.y + aspU[8 + j] * lo.z + aspU[12 + j] * lo.w
            + aspU[16 + j] * hi.x + aspU[20 + j] * hi.y + aspU[24 + j] * hi.z + aspU[28 + j] * hi.w;
    }
    return tt;
}

__device__ __forceinline__ void down_u(const float* r8, const float* aspD, float* u) {
    u[0] = u[1] = u[2] = u[3] = 0.f;
    #pragma unroll
    for (int i = 0; i < 8; i++) {
        u[0] += aspD[i * 4 + 0] * r8[i];
        u[1] += aspD[i * 4 + 1] * r8[i];
        u[2] += aspD[i * 4 + 2] * r8[i];
        u[3] += aspD[i * 4 + 3] * r8[i];
    }
}

__device__ __forceinline__ float spin_pos(float* p) {
    float v = atomicAdd(p, 0.f);
    while (!(v > 0.f)) { __builtin_amdgcn_s_sleep(1); v = atomicAdd(p, 0.f); }
    return v;
}
__device__ __forceinline__ float spin_sent(float* p) {
    float v = atomicAdd(p, 0.f);
    while (__float_as_uint(v) == SENTINEL) { __builtin_amdgcn_s_sleep(1); v = atomicAdd(p, 0.f); }
    return v;
}

// ---------------- K1: B logsumexp partials + sentinel-init channels ----------------
__global__ __launch_bounds__(256) void k_pre(const float* __restrict__ B, float* __restrict__ ws) {
    const int x = blockIdx.x, t = threadIdx.x;
    const int lane = t & 63, wv = t >> 6;
    __shared__ float s_stage[128];
    if (x < 64) {
        unsigned* wu = (unsigned*)ws;
        for (int i = t; i < 4096; i += 256) wu[WS_SG + (size_t)x * 4096 + i] = SENTINEL;
        if (t < 32) wu[WS_PG + x * 32 + t] = SENTINEL;
        for (int i = t; i < 768; i += 256) wu[WS_XCHG + (size_t)x * 768 + i] = SENTINEL;
    }
    const int cA = x >> 7, chunk = x & 127;
    const float* Bp = B + ((size_t)(cA * 8192) + chunk * 64) * 16;
    float mx = -3.4e38f, sE = 0.f;
    #pragma unroll
    for (int pass = 0; pass < 4; ++pass) {
        const float v = Bp[pass * 256 + t];
        const float nm = fmaxf(mx, v);
        sE = sE * __expf(mx - nm) + __expf(v - nm);
        mx = nm;
    }
    #pragma unroll
    for (int mk = 16; mk <= 32; mk <<= 1) {
        const float om = __shfl_xor(mx, mk), os = __shfl_xor(sE, mk);
        const float nm = fmaxf(mx, om);
        sE = sE * __expf(mx - nm) + os * __expf(om - nm);
        mx = nm;
    }
    if (lane < 16) { s_stage[(wv * 16 + lane) * 2] = mx; s_stage[(wv * 16 + lane) * 2 + 1] = sE; }
    __syncthreads();
    if (t < 16) {
        float M = s_stage[t * 2], S = s_stage[t * 2 + 1];
        #pragma unroll
        for (int w = 1; w < 4; ++w) {
            const float om = s_stage[(w * 16 + t) * 2], os = s_stage[(w * 16 + t) * 2 + 1];
            const float nm = fmaxf(M, om);
            S = S * __expf(M - nm) + os * __expf(om - nm);
            M = nm;
        }
        ws[WS_PART + ((t * 8 + cA) * 128 + chunk) * 2]     = M;
        ws[WS_PART + ((t * 8 + cA) * 128 + chunk) * 2 + 1] = S;
    }
}

// ---------------- K2: bleaf (0..255) + params (256..271) + internal-LGB gather (272..442) ----------------
__global__ __launch_bounds__(256) void k_mid(const int* __restrict__ labels,
                                             const float* __restrict__ A,
                                             const float* __restrict__ B,
                                             const float* __restrict__ Pi,
                                             const float* __restrict__ SP,
                                             float* __restrict__ ws) {
    const int x = blockIdx.x, t = threadIdx.x;
    if (x >= 256 && x < 272) {
        // ---- params for g = x-256 ----
        const int g = x - 256;
        __shared__ float s_st[256], s_expA[256], s_spe[4], s_pie[32];
        if (t < 128) {
            const int c2 = t >> 4, part = t & 15;
            const float* pp = ws + WS_PART + (size_t)(((g * 8 + c2) * 128 + part * 8) * 2);
            float M = -3.4e38f, S = 0.f;
            #pragma unroll
            for (int q = 0; q < 8; ++q) {
                const float om = pp[q * 2], os = pp[q * 2 + 1];
                const float nm = fmaxf(M, om);
                S = S * __expf(M - nm) + os * __expf(om - nm);
                M = nm;
            }
            s_st[t * 2] = M; s_st[t * 2 + 1] = S;
        }
        const float Av = A[t * 16 + g];
        s_expA[t] = __expf(Av);
        if (t < 4) s_spe[t] = __expf(SP[t * 16 + g]);
        if (t >= 32 && t < 64) s_pie[t - 32] = __expf(Pi[(t - 32) * 16 + g]);
        __syncthreads();
        if (t < 8) {
            float M = s_st[(t * 16) * 2], S = s_st[(t * 16) * 2 + 1];
            #pragma unroll
            for (int q = 1; q < 16; ++q) {
                const float om = s_st[(t * 16 + q) * 2], os = s_st[(t * 16 + q) * 2 + 1];
                const float nm = fmaxf(M, om);
                S = S * __expf(M - nm) + os * __expf(om - nm);
                M = nm;
            }
            ws[WS_LOGDEN + g * 8 + t] = M + __logf(S);
        }
        {
            const int kk = (t >> 2) & 7, jj = t & 3;
            float sumA = 0.f;
            #pragma unroll
            for (int i = 0; i < 8; ++i) sumA += s_expA[(i * 8 + kk) * 4 + jj];
            const float sps = s_spe[0] + s_spe[1] + s_spe[2] + s_spe[3];
            ws[WS_ASP + g * 256 + t]  = s_expA[t] / sumA * (s_spe[jj] / sps);
            ws[WS_LOGA + g * 256 + t] = Av - __logf(sumA);
            if (t < 4) ws[WS_LSP + g * 4 + t] = SP[t * 16 + g] - __logf(sps);
            if (t < 32) {
                float ps = 0.f;
                #pragma unroll
                for (int i2 = 0; i2 < 8; ++i2) ps += s_pie[i2 * 4 + (t & 3)];
                ws[WS_LPI + g * 32 + t] = Pi[t * 16 + g] - __logf(ps);
            }
        }
    } else {
        // both bleaf and gather branches need logden for all (c,g)
        __shared__ float s_ld[128];
        {
            const int pair = t >> 1, half = t & 1;
            const int c = pair >> 4, gg = pair & 15;
            const float* pp = ws + WS_PART + (size_t)(((gg * 8 + c) * 128 + half * 64) * 2);
            float M = -3.4e38f, S = 0.f;
            for (int q = 0; q < 64; ++q) {
                const float om = pp[q * 2], os = pp[q * 2 + 1];
                const float nm = fmaxf(M, om);
                S = S * __expf(M - nm) + os * __expf(om - nm);
                M = nm;
            }
            const float om = __shfl_xor(M, 1), os = __shfl_xor(S, 1);
            const float nm = fmaxf(M, om);
            S = S * __expf(M - nm) + os * __expf(om - nm);
            M = nm;
            if (half == 0) s_ld[c * 16 + gg] = M + __logf(S);
        }
        if (x < 256) {
            // ---- bleaf ----
            __shared__ float s_pie[512], s_smpi[512];
            s_pie[t] = __expf(Pi[t]);
            s_pie[256 + t] = __expf(Pi[256 + t]);
            __syncthreads();
            #pragma unroll
            for (int h = 0; h < 2; ++h) {
                const int idx = h * 256 + t;
                const int jg = idx & 63;
                float ps = 0.f;
                #pragma unroll
                for (int c2 = 0; c2 < 8; ++c2) ps += s_pie[c2 * 64 + jg];
                s_smpi[idx] = s_pie[idx] / ps;
            }
            __syncthreads();
            const int id = x * 256 + t;
            const int g = id & 15, p = id >> 4;
            const int pos = p & 3;
            float vals[8], ssum = 0.f;
            #pragma unroll
            for (int c = 0; c < 8; ++c) {
                const float v = s_smpi[(c * 4 + pos) * 16 + g] *
                    __expf(B[((size_t)(c * 8192) + 1365 + p) * 16 + g] - s_ld[c * 16 + g]);
                vals[c] = v; ssum += v;
            }
            const float inv = 1.f / ssum;
            float* o = ws + WS_BLEAF + (size_t)g * 32768 + (size_t)p * 8;
            *(float4*)o       = make_float4(vals[0] * inv, vals[1] * inv, vals[2] * inv, vals[3] * inv);
            *(float4*)(o + 4) = make_float4(vals[4] * inv, vals[5] * inv, vals[6] * inv, vals[7] * inv);
        } else {
            // ---- internal-node LGB gather: thread per (b,node,c), nodes 0..1364 ----
            __syncthreads();
            const int item = (x - 272) * 256 + t;   // 43680 = 4b * 1365node * 8c
            if (item < 43680) {
                const int b = item / 10920;
                const int rem = item - b * 10920;
                const int node = rem >> 3, c = rem & 7;
                const int lv = labels[b * 5461 + node];
                const float* bp = B + ((size_t)(c * 8192) + lv) * 16;
                const float4 q0 = *(const float4*)bp;
                const float4 q1 = *(const float4*)(bp + 4);
                const float4 q2 = *(const float4*)(bp + 8);
                const float4 q3 = *(const float4*)(bp + 12);
                const float vg[16] = {q0.x,q0.y,q0.z,q0.w, q1.x,q1.y,q1.z,q1.w,
                                      q2.x,q2.y,q2.z,q2.w, q3.x,q3.y,q3.z,q3.w};
                float* dst = ws + WS_LGB + (size_t)b * (16 * 10920) + (size_t)node * 8 + c;
                #pragma unroll
                for (int g = 0; g < 16; ++g)
                    dst[(size_t)g * 10920] = vg[g] - s_ld[c * 16 + g];
            }
        }
    }
}

// ---------------- K3: fused up + data-ready exchange + down + finalize ----------------
__global__ __launch_bounds__(256, 4) void k_tree(const int* __restrict__ labels,
                                                 const float* __restrict__ B,
                                                 float* __restrict__ ws,
                                                 float* __restrict__ out) {
    const int x = blockIdx.x, t = threadIdx.x;
    const int s = x & 15, g = (x >> 4) & 15, b = x >> 8;
    const int c8 = t & 7, lane = t & 63, wv = t >> 6;

    __shared__ __align__(16) float s_blf[2048];   // aliased as epilogue stage after d5
    __shared__ __align__(16) float s_lgb[720];
    __shared__ __align__(16) float s_lgbM[640];   // s==0 only: nodes 5..84 (contiguous in LGB)
    __shared__ __align__(16) float s_b5[512], s_q5[512], s_r5[512];
    __shared__ __align__(16) float s_b4[128], s_q4[128], s_r4[128];
    __shared__ __align__(16) float s_b3o[32], s_b3a[512], s_q3[32], s_r3[32];
    __shared__ __align__(16) float s_b2[128], s_q2[128], s_r2[128];
    __shared__ float s_b1[32], s_q1[32], s_r1[32], s_b0[8], s_q0[8];
    __shared__ float s_asp[256], s_lpi[32];
    __shared__ float s_scal[12], s_Alh[4];

    const float* lgbP = ws + WS_LGB + (size_t)(b * 16 + g) * 10920;

    // ---- register prefetch: 8 leaf-lgb values via direct label/B gather (consumed at d5) ----
    const float ldc8 = ws[WS_LOGDEN + g * 8 + c8];
    float rL[8];
    {
        const int lbase = b * 5461 + 1365 + s * 256;
        int labq[8];
        #pragma unroll
        for (int it = 0; it < 2; ++it) {
            const int p = (it * 256 + t) >> 3;
            #pragma unroll
            for (int j = 0; j < 4; ++j) labq[it * 4 + j] = labels[lbase + 4 * p + j];
        }
        #pragma unroll
        for (int z = 0; z < 8; ++z)
            rL[z] = B[((size_t)(c8 * 8192) + labq[z]) * 16 + g];
    }

    s_asp[t] = ws[WS_ASP + g * 256 + t];
    if (t < 32) s_lpi[t] = ws[WS_LPI + g * 32 + t];
    {
        const float4* bsrc = (const float4*)(ws + WS_BLEAF + (size_t)g * 32768 + (size_t)s * 2048);
        ((float4*)s_blf)[t] = bsrc[t];
        ((float4*)s_blf)[t + 256] = bsrc[t + 256];
    }
    #pragma unroll
    for (int it = 0; it < 3; ++it) {              // internal-lgb: dense segment loads
        const int q = it * 256 + t;
        if (q < 720) {
            const int nl = q >> 3, c = q & 7;
            s_lgb[q] = lgbP[node_id(nl, s) * 8 + c];
        }
    }
    if (s == 0) {                                 // nodes 5..84: one contiguous run
        #pragma unroll
        for (int it = 0; it < 3; ++it) {
            const int idx = it * 256 + t;
            if (idx < 640) s_lgbM[idx] = lgbP[40 + idx];
        }
    }
    __syncthreads();

    float aspR[32];   // UP layout: [k*4+j] = A_SP[i=c8,k,j]
    #pragma unroll
    for (int k = 0; k < 8; ++k)
        #pragma unroll
        for (int j = 0; j < 4; ++j) aspR[k * 4 + j] = s_asp[(c8 * 8 + k) * 4 + j];

    // ---- up-sweep (own subtree), all state in LDS ----
    #pragma unroll
    for (int it = 0; it < 2; ++it) {              // L5: 64 nodes
        const int p = (it * 256 + t) >> 3;
        const float tt = up_tt(s_blf + p * 32, aspR);
        const float bu = tt * __expf(s_lgb[(26 + p) * 8 + c8]);
        float ssum = bu;
        ssum += __shfl_xor(ssum, 1); ssum += __shfl_xor(ssum, 2); ssum += __shfl_xor(ssum, 4);
        const float beta = bu / ssum;
        s_b5[p * 8 + c8] = beta; s_q5[p * 8 + c8] = beta / tt;
    }
    __syncthreads();
    if (t < 128) {                                // L4: 16
        const int p = t >> 3;
        const float tt = up_tt(s_b5 + p * 32, aspR);
        const float bu = tt * __expf(s_lgb[(10 + p) * 8 + c8]);
        float ssum = bu;
        ssum += __shfl_xor(ssum, 1); ssum += __shfl_xor(ssum, 2); ssum += __shfl_xor(ssum, 4);
        const float beta = bu / ssum;
        s_b4[p * 8 + c8] = beta; s_q4[p * 8 + c8] = beta / tt;
    }
    __syncthreads();
    if (t < 32) {                                 // L3: 4
        const int p = t >> 3;
        const float tt = up_tt(s_b4 + p * 32, aspR);
        const float bu = tt * __expf(s_lgb[(6 + p) * 8 + c8]);
        float ssum = bu;
        ssum += __shfl_xor(ssum, 1); ssum += __shfl_xor(ssum, 2); ssum += __shfl_xor(ssum, 4);
        const float beta = bu / ssum;
        s_b3o[p * 8 + c8] = beta; s_q3[p * 8 + c8] = beta / tt;
    }
    __syncthreads();
    float* X = ws + WS_XCHG + (size_t)(b * 16 + g) * 768;
    if (t < 8) {                                  // L2 -> exchange (value IS the ready flag)
        const float tt = up_tt(s_b3o, aspR);
        const float bu = tt * __expf(s_lgb[5 * 8 + c8]);
        float ssum = bu;
        ssum += __shfl_xor(ssum, 1); ssum += __shfl_xor(ssum, 2); ssum += __shfl_xor(ssum, 4);
        const float beta = bu / ssum;
        atomicExch(&X[s * 8 + c8], beta);
        atomicExch(&X[128 + s * 8 + c8], beta / tt);
    }
    if (t < 32) atomicExch(&X[256 + s * 32 + t], s_b3o[t]);

    // ---- data-ready consume: spin per element ----
    {
        const float v = spin_pos(&X[t]);
        if (t < 128) s_b2[t] = v; else s_q2[t - 128] = v;
        if (s == 0) {
            s_b3a[t] = spin_pos(&X[256 + t]);
            s_b3a[256 + t] = spin_pos(&X[512 + t]);
        }
    }
    __syncthreads();

    // ---- middle up (replicated per subtree) ----
    if (t < 32) {                                 // L1
        const int p = t >> 3;
        const float tt = up_tt(s_b2 + p * 32, aspR);
        const float bu = tt * __expf(s_lgb[(1 + p) * 8 + c8]);
        float ssum = bu;
        ssum += __shfl_xor(ssum, 1); ssum += __shfl_xor(ssum, 2); ssum += __shfl_xor(ssum, 4);
        s_b1[p * 8 + c8] = bu / ssum;
        s_q1[p * 8 + c8] = (bu / ssum) / tt;
    }
    __syncthreads();
    if (t < 8) {                                  // L0
        const float tt = up_tt(s_b1, aspR);
        const float bu = tt * __expf(s_lgb[c8]);
        float ssum = bu;
        ssum += __shfl_xor(ssum, 1); ssum += __shfl_xor(ssum, 2); ssum += __shfl_xor(ssum, 4);
        s_b0[c8] = bu / ssum;
        s_q0[c8] = (bu / ssum) / tt;
    }
    __syncthreads();

    #pragma unroll
    for (int i = 0; i < 8; ++i)                   // DOWN layout: [i*4+j] = A_SP[i,k=c8,j]
        #pragma unroll
        for (int j = 0; j < 4; ++j) aspR[i * 4 + j] = s_asp[(i * 8 + c8) * 4 + j];

    float pB = 0.f, pPi = 0.f;
    float Sacc[32];
    #pragma unroll
    for (int z = 0; z < 32; z++) Sacc[z] = 0.f;

    // d=0
    if (t < 8) {
        float r8[8], u[4];
        #pragma unroll
        for (int i = 0; i < 8; i++) r8[i] = s_q0[i];
        down_u(r8, aspR, u);
        #pragma unroll
        for (int j = 0; j < 4; j++) s_r1[j * 8 + c8] = s_q1[j * 8 + c8] * u[j];
        if (s == 0) {
            pB += s_b0[c8] * s_lgb[c8];
            #pragma unroll
            for (int j = 0; j < 4; j++) {
                const float bc = s_b1[j * 8 + c8];
                pB += bc * u[j] * s_lgb[(1 + j) * 8 + c8];
                #pragma unroll
                for (int i = 0; i < 8; i++) Sacc[i * 4 + j] += r8[i] * bc;
            }
        }
    }
    __syncthreads();
    // d=1
    if (t < 32) {
        const int p = t >> 3;
        float r8[8], u[4];
        #pragma unroll
        for (int i = 0; i < 8; i++) r8[i] = s_r1[p * 8 + i];
        down_u(r8, aspR, u);
        #pragma unroll
        for (int j = 0; j < 4; j++) {
            const int ch = 4 * p + j;
            s_r2[ch * 8 + c8] = s_q2[ch * 8 + c8] * u[j];
            if (s == 0) {
                const float bc = s_b2[ch * 8 + c8];
                pB += bc * u[j] * s_lgbM[ch * 8 + c8];
                #pragma unroll
                for (int i = 0; i < 8; i++) Sacc[i * 4 + j] += r8[i] * bc;
            }
        }
    }
    __syncthreads();
    // d=2
    if (t < 128) {
        const int p = t >> 3;
        float r8[8], u[4];
        #pragma unroll
        for (int i = 0; i < 8; i++) r8[i] = s_r2[p * 8 + i];
        down_u(r8, aspR, u);
        #pragma unroll
        for (int j = 0; j < 4; j++) {
            const int ch = 4 * p + j;
            if (p == s) s_r3[j * 8 + c8] = s_q3[j * 8 + c8] * u[j];
            if (s == 0) {
                const float bc = s_b3a[ch * 8 + c8];
                pB += bc * u[j] * s_lgbM[(16 + ch) * 8 + c8];
                #pragma unroll
                for (int i = 0; i < 8; i++) Sacc[i * 4 + j] += r8[i] * bc;
            }
        }
    }
    __syncthreads();
    // d=3
    if (t < 32) {
        const int p = t >> 3;
        float r8[8], u[4];
        #pragma unroll
        for (int i = 0; i < 8; i++) r8[i] = s_r3[p * 8 + i];
        down_u(r8, aspR, u);
        #pragma unroll
        for (int j = 0; j < 4; j++) {
            const int ch = 4 * p + j;
            const float bc = s_b4[ch * 8 + c8];
            pB += bc * u[j] * s_lgb[(10 + ch) * 8 + c8];
            s_r4[ch * 8 + c8] = s_q4[ch * 8 + c8] * u[j];
            #pragma unroll
            for (int i = 0; i < 8; i++) Sacc[i * 4 + j] += r8[i] * bc;
        }
    }
    __syncthreads();
    // d=4
    if (t < 128) {
        const int p = t >> 3;
        float r8[8], u[4];
        #pragma unroll
        for (int i = 0; i < 8; i++) r8[i] = s_r4[p * 8 + i];
        down_u(r8, aspR, u);
        #pragma unroll
        for (int j = 0; j < 4; j++) {
            const int ch = 4 * p + j;
            const float bc = s_b5[ch * 8 + c8];
            pB += bc * u[j] * s_lgb[(26 + ch) * 8 + c8];
            s_r5[ch * 8 + c8] = s_q5[ch * 8 + c8] * u[j];
            #pragma unroll
            for (int i = 0; i < 8; i++) Sacc[i * 4 + j] += r8[i] * bc;
        }
    }
    __syncthreads();
    // d=5 (leaves): leaf-lgb from registers
    #pragma unroll
    for (int it = 0; it < 2; ++it) {
        const int p = (it * 256 + t) >> 3;
        float r8[8], u[4];
        #pragma unroll
        for (int i = 0; i < 8; i++) r8[i] = s_r5[p * 8 + i];
        down_u(r8, aspR, u);
        #pragma unroll
        for (int j = 0; j < 4; j++) {
            const int q = 4 * p + j;
            const float bc = s_blf[q * 8 + c8];
            const float e6 = bc * u[j];
            pB += e6 * (rL[it * 4 + j] - ldc8);
            pPi += e6 * s_lpi[c8 * 4 + j];
            #pragma unroll
            for (int i = 0; i < 8; i++) Sacc[i * 4 + j] += r8[i] * bc;
        }
    }

    // ---- epilogue: reduce, publish per-s slots (value == ready flag) ----
    #pragma unroll
    for (int z = 0; z < 32; z++) {
        float v = Sacc[z];
        v += __shfl_xor(v, 8);
        v += __shfl_xor(v, 16);
        v += __shfl_xor(v, 32);
        Sacc[z] = v;
    }
    #pragma unroll
    for (int m = 1; m < 64; m <<= 1) { pB += __shfl_xor(pB, m); pPi += __shfl_xor(pPi, m); }
    float* s_stage = s_blf;                       // alias: blf dead after d5
    __syncthreads();
    if (lane < 8) {
        #pragma unroll
        for (int z = 0; z < 32; z++)
            s_stage[wv * 256 + ((z >> 2) * 8 + lane) * 4 + (z & 3)] = Sacc[z];
    }
    if (lane == 0) { s_scal[wv] = pB; s_scal[4 + wv] = pPi; }
    __syncthreads();
    {
        const float TS = s_stage[t] + s_stage[256 + t] + s_stage[512 + t] + s_stage[768 + t];
        float* SgW = ws + WS_SG + ((size_t)(b * 16 + g) * 16 + s) * 256;
        atomicExch(&SgW[t], TS);                  // TS strictly > 0
        float* PgW = ws + WS_PG + ((size_t)(b * 16 + g) * 16 + s) * 2;
        if (t == 0) atomicExch(&PgW[0], s_scal[0] + s_scal[1] + s_scal[2] + s_scal[3]);
        if (t == 1) atomicExch(&PgW[1], s_scal[4] + s_scal[5] + s_scal[6] + s_scal[7]);
    }

    // ---- finalize: block s==15 spin-reads all 16 per-s slots ----
    if (s == 15) {
        if (t < 4) s_Alh[t] = 0.f;
        float Ssum = 0.f;
        float* SgB = ws + WS_SG + (size_t)(b * 16 + g) * 4096;
        #pragma unroll
        for (int sp = 0; sp < 16; ++sp)
            Ssum += spin_pos(&SgB[sp * 256 + t]);
        if (t < 2) {
            float* PgB = ws + WS_PG + (size_t)(b * 16 + g) * 32;
            float tot = 0.f;
            #pragma unroll
            for (int sp = 0; sp < 16; ++sp)
                tot += spin_sent(&PgB[sp * 2 + t]);
            s_scal[8 + t] = tot;
        }
        __syncthreads();
        const float val = s_asp[t] * Ssum;
        atomicAdd(&s_Alh[t & 3], val * ws[WS_LOGA + g * 256 + t]);
        __syncthreads();
        out[(size_t)b * 4096 + t * 16 + g] =
            -(s_Alh[t & 3] + s_scal[8] + s_scal[9] + val * ws[WS_LSP + g * 4 + (t & 3)]);
    }
}

extern "C" void kernel_launch(void* const* d_in, const int* in_sizes, int n_in,
                              void* d_out, int out_size, void* d_ws, size_t ws_size,
                              hipStream_t stream) {
    (void)in_sizes; (void)n_in; (void)out_size; (void)ws_size;
    const int* labels = (const int*)d_in[0];
    const float* A  = (const float*)d_in[1];
    const float* B  = (const float*)d_in[2];
    const float* Pi = (const float*)d_in[3];
    const float* SP = (const float*)d_in[4];
    float* ws = (float*)d_ws;
    float* out = (float*)d_out;

    hipLaunchKernelGGL(k_pre,  dim3(1024), dim3(256), 0, stream, B, ws);
    hipLaunchKernelGGL(k_mid,  dim3(443),  dim3(256), 0, stream, labels, A, B, Pi, SP, ws);
    hipLaunchKernelGGL(k_tree, dim3(1024), dim3(256), 0, stream, labels, B, ws, out);
}

// Round 13
// 115.852 us; speedup vs baseline: 1.0817x; 1.0297x over previous
//
#include <hip/hip_runtime.h>

// C=8, L=4, M=8192, NGEN=16, DEPTH=6, BATCH=4, N=5461
// Level starts: L0:0 L1:1 L2:5 L3:21 L4:85 L5:341 leaves:1365
// Subtree s (0..15) rooted at L2 node 5+s.

// ---- workspace layout (4B units) ----
#define WS_PART   0        // 32768
#define WS_LOGDEN 32768    // 128  [g*8+c]
#define WS_ASP    32896    // 4096 [g*256 + (i*8+k)*4+j]
#define WS_LOGA   36992    // 4096
#define WS_LPI    41088    // 512
#define WS_LSP    41600    // 64
#define WS_BLEAF  41664    // 524288 [g*32768 + p*8 + c]
#define WS_LGB    565952   // 698880 = 64*10920: RAW B rows [b][g][node*8+c], internal nodes
#define WS_XCHG   1264832  // 64*768 per (b,g): [B2 0..128 | Q2 128..256 | B3 256..768]
#define WS_SG     1313984  // 64*16*256  per (b,g): [s][t]
#define WS_PG     1576128  // 64*16*2    per (b,g): [s][{pB,pPi}]
#define SENTINEL  0xAAAAAAAAu

__device__ __forceinline__ int node_id(int nl, int s) {
    if (nl == 0) return 0;
    if (nl < 5)  return nl;
    if (nl == 5) return 5 + s;
    if (nl < 10) return 21 + 4 * s + (nl - 6);
    if (nl < 26) return 85 + 16 * s + (nl - 10);
    return 341 + 64 * s + (nl - 26);
}

__device__ __forceinline__ float up_tt(const float* bp, const float* aspU) {
    float tt = 0.f;
    #pragma unroll
    for (int j = 0; j < 4; j++) {
        float4 lo = *(const float4*)(bp + j * 8);
        float4 hi = *(const float4*)(bp + j * 8 + 4);
        tt += aspU[0 + j] * lo.x + aspU[4 + j] * lo.y + aspU[8 + j] * lo.z + aspU[12 + j] * lo.w
            + aspU[16 + j] * hi.x + aspU[20 + j] * hi.y + aspU[24 + j] * hi.z + aspU[28 + j] * hi.w;
    }
    return tt;
}

__device__ __forceinline__ void down_u(const float* r8, const float* aspD, float* u) {
    u[0] = u[1] = u[2] = u[3] = 0.f;
    #pragma unroll
    for (int i = 0; i < 8; i++) {
        u[0] += aspD[i * 4 + 0] * r8[i];
        u[1] += aspD[i * 4 + 1] * r8[i];
        u[2] += aspD[i * 4 + 2] * r8[i];
        u[3] += aspD[i * 4 + 3] * r8[i];
    }
}

__device__ __forceinline__ float spin_pos(float* p) {
    float v = atomicAdd(p, 0.f);
    while (!(v > 0.f)) { __builtin_amdgcn_s_sleep(4); v = atomicAdd(p, 0.f); }
    return v;
}
__device__ __forceinline__ float spin_sent(float* p) {
    float v = atomicAdd(p, 0.f);
    while (__float_as_uint(v) == SENTINEL) { __builtin_amdgcn_s_sleep(4); v = atomicAdd(p, 0.f); }
    return v;
}

// ---------------- K1: logsumexp partials (0..1023) + RAW LGB gather (1024..1194) + sentinel init ----------------
__global__ __launch_bounds__(256) void k_pre(const int* __restrict__ labels,
                                             const float* __restrict__ B,
                                             float* __restrict__ ws) {
    const int x = blockIdx.x, t = threadIdx.x;
    if (x >= 1024) {
        // ---- raw internal-node LGB gather (no logden needed) ----
        const int item = (x - 1024) * 256 + t;   // 43680 = 4b * 1365node * 8c
        if (item < 43680) {
            const int b = item / 10920;
            const int rem = item - b * 10920;
            const int node = rem >> 3, c = rem & 7;
            const int lv = labels[b * 5461 + node];
            const float* bp = B + ((size_t)(c * 8192) + lv) * 16;
            const float4 q0 = *(const float4*)bp;
            const float4 q1 = *(const float4*)(bp + 4);
            const float4 q2 = *(const float4*)(bp + 8);
            const float4 q3 = *(const float4*)(bp + 12);
            const float vg[16] = {q0.x,q0.y,q0.z,q0.w, q1.x,q1.y,q1.z,q1.w,
                                  q2.x,q2.y,q2.z,q2.w, q3.x,q3.y,q3.z,q3.w};
            float* dst = ws + WS_LGB + (size_t)b * (16 * 10920) + (size_t)node * 8 + c;
            #pragma unroll
            for (int g = 0; g < 16; ++g)
                dst[(size_t)g * 10920] = vg[g];
        }
        return;
    }
    const int lane = t & 63, wv = t >> 6;
    __shared__ float s_stage[128];
    if (x < 64) {
        unsigned* wu = (unsigned*)ws;
        for (int i = t; i < 4096; i += 256) wu[WS_SG + (size_t)x * 4096 + i] = SENTINEL;
        if (t < 32) wu[WS_PG + x * 32 + t] = SENTINEL;
        for (int i = t; i < 768; i += 256) wu[WS_XCHG + (size_t)x * 768 + i] = SENTINEL;
    }
    const int cA = x >> 7, chunk = x & 127;
    const float* Bp = B + ((size_t)(cA * 8192) + chunk * 64) * 16;
    float mx = -3.4e38f, sE = 0.f;
    #pragma unroll
    for (int pass = 0; pass < 4; ++pass) {
        const float v = Bp[pass * 256 + t];
        const float nm = fmaxf(mx, v);
        sE = sE * __expf(mx - nm) + __expf(v - nm);
        mx = nm;
    }
    #pragma unroll
    for (int mk = 16; mk <= 32; mk <<= 1) {
        const float om = __shfl_xor(mx, mk), os = __shfl_xor(sE, mk);
        const float nm = fmaxf(mx, om);
        sE = sE * __expf(mx - nm) + os * __expf(om - nm);
        mx = nm;
    }
    if (lane < 16) { s_stage[(wv * 16 + lane) * 2] = mx; s_stage[(wv * 16 + lane) * 2 + 1] = sE; }
    __syncthreads();
    if (t < 16) {
        float M = s_stage[t * 2], S = s_stage[t * 2 + 1];
        #pragma unroll
        for (int w = 1; w < 4; ++w) {
            const float om = s_stage[(w * 16 + t) * 2], os = s_stage[(w * 16 + t) * 2 + 1];
            const float nm = fmaxf(M, om);
            S = S * __expf(M - nm) + os * __expf(om - nm);
            M = nm;
        }
        ws[WS_PART + ((t * 8 + cA) * 128 + chunk) * 2]     = M;
        ws[WS_PART + ((t * 8 + cA) * 128 + chunk) * 2 + 1] = S;
    }
}

// ---------------- K2: bleaf (0..255) + params (256..271) ----------------
__global__ __launch_bounds__(256) void k_mid(const float* __restrict__ A,
                                             const float* __restrict__ B,
                                             const float* __restrict__ Pi,
                                             const float* __restrict__ SP,
                                             float* __restrict__ ws) {
    const int x = blockIdx.x, t = threadIdx.x;
    if (x >= 256) {
        // ---- params for g = x-256 ----
        const int g = x - 256;
        __shared__ float s_st[256], s_expA[256], s_spe[4], s_pie[32];
        if (t < 128) {
            const int c2 = t >> 4, part = t & 15;
            const float* pp = ws + WS_PART + (size_t)(((g * 8 + c2) * 128 + part * 8) * 2);
            float M = -3.4e38f, S = 0.f;
            #pragma unroll
            for (int q = 0; q < 8; ++q) {
                const float om = pp[q * 2], os = pp[q * 2 + 1];
                const float nm = fmaxf(M, om);
                S = S * __expf(M - nm) + os * __expf(om - nm);
                M = nm;
            }
            s_st[t * 2] = M; s_st[t * 2 + 1] = S;
        }
        const float Av = A[t * 16 + g];
        s_expA[t] = __expf(Av);
        if (t < 4) s_spe[t] = __expf(SP[t * 16 + g]);
        if (t >= 32 && t < 64) s_pie[t - 32] = __expf(Pi[(t - 32) * 16 + g]);
        __syncthreads();
        if (t < 8) {
            float M = s_st[(t * 16) * 2], S = s_st[(t * 16) * 2 + 1];
            #pragma unroll
            for (int q = 1; q < 16; ++q) {
                const float om = s_st[(t * 16 + q) * 2], os = s_st[(t * 16 + q) * 2 + 1];
                const float nm = fmaxf(M, om);
                S = S * __expf(M - nm) + os * __expf(om - nm);
                M = nm;
            }
            ws[WS_LOGDEN + g * 8 + t] = M + __logf(S);
        }
        {
            const int kk = (t >> 2) & 7, jj = t & 3;
            float sumA = 0.f;
            #pragma unroll
            for (int i = 0; i < 8; ++i) sumA += s_expA[(i * 8 + kk) * 4 + jj];
            const float sps = s_spe[0] + s_spe[1] + s_spe[2] + s_spe[3];
            ws[WS_ASP + g * 256 + t]  = s_expA[t] / sumA * (s_spe[jj] / sps);
            ws[WS_LOGA + g * 256 + t] = Av - __logf(sumA);
            if (t < 4) ws[WS_LSP + g * 4 + t] = SP[t * 16 + g] - __logf(sps);
            if (t < 32) {
                float ps = 0.f;
                #pragma unroll
                for (int i2 = 0; i2 < 8; ++i2) ps += s_pie[i2 * 4 + (t & 3)];
                ws[WS_LPI + g * 32 + t] = Pi[t * 16 + g] - __logf(ps);
            }
        }
    } else {
        // ---- bleaf (needs logden from PART) ----
        __shared__ float s_ld[128], s_pie[512], s_smpi[512];
        {
            const int pair = t >> 1, half = t & 1;
            const int c = pair >> 4, gg = pair & 15;
            const float* pp = ws + WS_PART + (size_t)(((gg * 8 + c) * 128 + half * 64) * 2);
            float M = -3.4e38f, S = 0.f;
            for (int q = 0; q < 64; ++q) {
                const float om = pp[q * 2], os = pp[q * 2 + 1];
                const float nm = fmaxf(M, om);
                S = S * __expf(M - nm) + os * __expf(om - nm);
                M = nm;
            }
            const float om = __shfl_xor(M, 1), os = __shfl_xor(S, 1);
            const float nm = fmaxf(M, om);
            S = S * __expf(M - nm) + os * __expf(om - nm);
            M = nm;
            if (half == 0) s_ld[c * 16 + gg] = M + __logf(S);
        }
        s_pie[t] = __expf(Pi[t]);
        s_pie[256 + t] = __expf(Pi[256 + t]);
        __syncthreads();
        #pragma unroll
        for (int h = 0; h < 2; ++h) {
            const int idx = h * 256 + t;
            const int jg = idx & 63;
            float ps = 0.f;
            #pragma unroll
            for (int c2 = 0; c2 < 8; ++c2) ps += s_pie[c2 * 64 + jg];
            s_smpi[idx] = s_pie[idx] / ps;
        }
        __syncthreads();
        const int id = x * 256 + t;
        const int g = id & 15, p = id >> 4;
        const int pos = p & 3;
        float vals[8], ssum = 0.f;
        #pragma unroll
        for (int c = 0; c < 8; ++c) {
            const float v = s_smpi[(c * 4 + pos) * 16 + g] *
                __expf(B[((size_t)(c * 8192) + 1365 + p) * 16 + g] - s_ld[c * 16 + g]);
            vals[c] = v; ssum += v;
        }
        const float inv = 1.f / ssum;
        float* o = ws + WS_BLEAF + (size_t)g * 32768 + (size_t)p * 8;
        *(float4*)o       = make_float4(vals[0] * inv, vals[1] * inv, vals[2] * inv, vals[3] * inv);
        *(float4*)(o + 4) = make_float4(vals[4] * inv, vals[5] * inv, vals[6] * inv, vals[7] * inv);
    }
}

// ---------------- K3: fused up + data-ready exchange + down + finalize ----------------
__global__ __launch_bounds__(256, 4) void k_tree(const int* __restrict__ labels,
                                                 const float* __restrict__ B,
                                                 float* __restrict__ ws,
                                                 float* __restrict__ out) {
    const int x = blockIdx.x, t = threadIdx.x;
    const int s = x & 15, g = (x >> 4) & 15, b = x >> 8;
    const int c8 = t & 7, lane = t & 63, wv = t >> 6;

    __shared__ __align__(16) float s_blf[2048];   // aliased as epilogue stage after d5
    __shared__ __align__(16) float s_lgb[720];
    __shared__ __align__(16) float s_lgbM[640];   // s==0 only: nodes 5..84 (contiguous in LGB)
    __shared__ __align__(16) float s_b5[512], s_q5[512], s_r5[512];
    __shared__ __align__(16) float s_b4[128], s_q4[128], s_r4[128];
    __shared__ __align__(16) float s_b3o[32], s_b3a[512], s_q3[32], s_r3[32];
    __shared__ __align__(16) float s_b2[128], s_q2[128], s_r2[128];
    __shared__ float s_b1[32], s_q1[32], s_r1[32], s_b0[8], s_q0[8];
    __shared__ float s_asp[256], s_lpi[32];
    __shared__ float s_scal[12], s_Alh[4];

    const float* lgbP = ws + WS_LGB + (size_t)(b * 16 + g) * 10920;

    // ---- register prefetch: 8 leaf-lgb values via direct label/B gather (consumed at d5) ----
    const float ldc8 = ws[WS_LOGDEN + g * 8 + c8];
    float rL[8];
    {
        const int lbase = b * 5461 + 1365 + s * 256;
        int labq[8];
        #pragma unroll
        for (int it = 0; it < 2; ++it) {
            const int p = (it * 256 + t) >> 3;
            #pragma unroll
            for (int j = 0; j < 4; ++j) labq[it * 4 + j] = labels[lbase + 4 * p + j];
        }
        #pragma unroll
        for (int z = 0; z < 8; ++z)
            rL[z] = B[((size_t)(c8 * 8192) + labq[z]) * 16 + g];
    }

    s_asp[t] = ws[WS_ASP + g * 256 + t];
    if (t < 32) s_lpi[t] = ws[WS_LPI + g * 32 + t];
    {
        const float4* bsrc = (const float4*)(ws + WS_BLEAF + (size_t)g * 32768 + (size_t)s * 2048);
        ((float4*)s_blf)[t] = bsrc[t];
        ((float4*)s_blf)[t + 256] = bsrc[t + 256];
    }
    // internal-lgb: dense loads; c = q&7 == t&7 == c8, so subtract ldc8
    #pragma unroll
    for (int it = 0; it < 3; ++it) {
        const int q = it * 256 + t;
        if (q < 720) {
            const int nl = q >> 3;
            s_lgb[q] = lgbP[node_id(nl, s) * 8 + c8] - ldc8;
        }
    }
    if (s == 0) {                                 // nodes 5..84: contiguous; idx&7 == c8
        #pragma unroll
        for (int it = 0; it < 3; ++it) {
            const int idx = it * 256 + t;
            if (idx < 640) s_lgbM[idx] = lgbP[40 + idx] - ldc8;
        }
    }
    __syncthreads();

    float aspR[32];   // UP layout: [k*4+j] = A_SP[i=c8,k,j]
    #pragma unroll
    for (int k = 0; k < 8; ++k)
        #pragma unroll
        for (int j = 0; j < 4; ++j) aspR[k * 4 + j] = s_asp[(c8 * 8 + k) * 4 + j];

    // ---- up-sweep (own subtree), all state in LDS ----
    #pragma unroll
    for (int it = 0; it < 2; ++it) {              // L5: 64 nodes
        const int p = (it * 256 + t) >> 3;
        const float tt = up_tt(s_blf + p * 32, aspR);
        const float bu = tt * __expf(s_lgb[(26 + p) * 8 + c8]);
        float ssum = bu;
        ssum += __shfl_xor(ssum, 1); ssum += __shfl_xor(ssum, 2); ssum += __shfl_xor(ssum, 4);
        const float beta = bu / ssum;
        s_b5[p * 8 + c8] = beta; s_q5[p * 8 + c8] = beta / tt;
    }
    __syncthreads();
    if (t < 128) {                                // L4: 16
        const int p = t >> 3;
        const float tt = up_tt(s_b5 + p * 32, aspR);
        const float bu = tt * __expf(s_lgb[(10 + p) * 8 + c8]);
        float ssum = bu;
        ssum += __shfl_xor(ssum, 1); ssum += __shfl_xor(ssum, 2); ssum += __shfl_xor(ssum, 4);
        const float beta = bu / ssum;
        s_b4[p * 8 + c8] = beta; s_q4[p * 8 + c8] = beta / tt;
    }
    __syncthreads();
    if (t < 32) {                                 // L3: 4
        const int p = t >> 3;
        const float tt = up_tt(s_b4 + p * 32, aspR);
        const float bu = tt * __expf(s_lgb[(6 + p) * 8 + c8]);
        float ssum = bu;
        ssum += __shfl_xor(ssum, 1); ssum += __shfl_xor(ssum, 2); ssum += __shfl_xor(ssum, 4);
        const float beta = bu / ssum;
        s_b3o[p * 8 + c8] = beta; s_q3[p * 8 + c8] = beta / tt;
    }
    __syncthreads();
    float* X = ws + WS_XCHG + (size_t)(b * 16 + g) * 768;
    if (t < 8) {                                  // L2 -> exchange (value IS the ready flag)
        const float tt = up_tt(s_b3o, aspR);
        const float bu = tt * __expf(s_lgb[5 * 8 + c8]);
        float ssum = bu;
        ssum += __shfl_xor(ssum, 1); ssum += __shfl_xor(ssum, 2); ssum += __shfl_xor(ssum, 4);
        const float beta = bu / ssum;
        atomicExch(&X[s * 8 + c8], beta);
        atomicExch(&X[128 + s * 8 + c8], beta / tt);
    }
    if (t < 32) atomicExch(&X[256 + s * 32 + t], s_b3o[t]);

    // ---- data-ready consume: spin per element ----
    {
        const float v = spin_pos(&X[t]);
        if (t < 128) s_b2[t] = v; else s_q2[t - 128] = v;
        if (s == 0) {
            s_b3a[t] = spin_pos(&X[256 + t]);
            s_b3a[256 + t] = spin_pos(&X[512 + t]);
        }
    }
    __syncthreads();

    // ---- middle up (replicated per subtree) ----
    if (t < 32) {                                 // L1
        const int p = t >> 3;
        const float tt = up_tt(s_b2 + p * 32, aspR);
        const float bu = tt * __expf(s_lgb[(1 + p) * 8 + c8]);
        float ssum = bu;
        ssum += __shfl_xor(ssum, 1); ssum += __shfl_xor(ssum, 2); ssum += __shfl_xor(ssum, 4);
        s_b1[p * 8 + c8] = bu / ssum;
        s_q1[p * 8 + c8] = (bu / ssum) / tt;
    }
    __syncthreads();
    if (t < 8) {                                  // L0
        const float tt = up_tt(s_b1, aspR);
        const float bu = tt * __expf(s_lgb[c8]);
        float ssum = bu;
        ssum += __shfl_xor(ssum, 1); ssum += __shfl_xor(ssum, 2); ssum += __shfl_xor(ssum, 4);
        s_b0[c8] = bu / ssum;
        s_q0[c8] = (bu / ssum) / tt;
    }
    __syncthreads();

    #pragma unroll
    for (int i = 0; i < 8; ++i)                   // DOWN layout: [i*4+j] = A_SP[i,k=c8,j]
        #pragma unroll
        for (int j = 0; j < 4; ++j) aspR[i * 4 + j] = s_asp[(i * 8 + c8) * 4 + j];

    float pB = 0.f, pPi = 0.f;
    float Sacc[32];
    #pragma unroll
    for (int z = 0; z < 32; z++) Sacc[z] = 0.f;

    // d=0
    if (t < 8) {
        float r8[8], u[4];
        #pragma unroll
        for (int i = 0; i < 8; i++) r8[i] = s_q0[i];
        down_u(r8, aspR, u);
        #pragma unroll
        for (int j = 0; j < 4; j++) s_r1[j * 8 + c8] = s_q1[j * 8 + c8] * u[j];
        if (s == 0) {
            pB += s_b0[c8] * s_lgb[c8];
            #pragma unroll
            for (int j = 0; j < 4; j++) {
                const float bc = s_b1[j * 8 + c8];
                pB += bc * u[j] * s_lgb[(1 + j) * 8 + c8];
                #pragma unroll
                for (int i = 0; i < 8; i++) Sacc[i * 4 + j] += r8[i] * bc;
            }
        }
    }
    __syncthreads();
    // d=1
    if (t < 32) {
        const int p = t >> 3;
        float r8[8], u[4];
        #pragma unroll
        for (int i = 0; i < 8; i++) r8[i] = s_r1[p * 8 + i];
        down_u(r8, aspR, u);
        #pragma unroll
        for (int j = 0; j < 4; j++) {
            const int ch = 4 * p + j;
            s_r2[ch * 8 + c8] = s_q2[ch * 8 + c8] * u[j];
            if (s == 0) {
                const float bc = s_b2[ch * 8 + c8];
                pB += bc * u[j] * s_lgbM[ch * 8 + c8];
                #pragma unroll
                for (int i = 0; i < 8; i++) Sacc[i * 4 + j] += r8[i] * bc;
            }
        }
    }
    __syncthreads();
    // d=2
    if (t < 128) {
        const int p = t >> 3;
        float r8[8], u[4];
        #pragma unroll
        for (int i = 0; i < 8; i++) r8[i] = s_r2[p * 8 + i];
        down_u(r8, aspR, u);
        #pragma unroll
        for (int j = 0; j < 4; j++) {
            const int ch = 4 * p + j;
            if (p == s) s_r3[j * 8 + c8] = s_q3[j * 8 + c8] * u[j];
            if (s == 0) {
                const float bc = s_b3a[ch * 8 + c8];
                pB += bc * u[j] * s_lgbM[(16 + ch) * 8 + c8];
                #pragma unroll
                for (int i = 0; i < 8; i++) Sacc[i * 4 + j] += r8[i] * bc;
            }
        }
    }
    __syncthreads();
    // d=3
    if (t < 32) {
        const int p = t >> 3;
        float r8[8], u[4];
        #pragma unroll
        for (int i = 0; i < 8; i++) r8[i] = s_r3[p * 8 + i];
        down_u(r8, aspR, u);
        #pragma unroll
        for (int j = 0; j < 4; j++) {
            const int ch = 4 * p + j;
            const float bc = s_b4[ch * 8 + c8];
            pB += bc * u[j] * s_lgb[(10 + ch) * 8 + c8];
            s_r4[ch * 8 + c8] = s_q4[ch * 8 + c8] * u[j];
            #pragma unroll
            for (int i = 0; i < 8; i++) Sacc[i * 4 + j] += r8[i] * bc;
        }
    }
    __syncthreads();
    // d=4
    if (t < 128) {
        const int p = t >> 3;
        float r8[8], u[4];
        #pragma unroll
        for (int i = 0; i < 8; i++) r8[i] = s_r4[p * 8 + i];
        down_u(r8, aspR, u);
        #pragma unroll
        for (int j = 0; j < 4; j++) {
            const int ch = 4 * p + j;
            const float bc = s_b5[ch * 8 + c8];
            pB += bc * u[j] * s_lgb[(26 + ch) * 8 + c8];
            s_r5[ch * 8 + c8] = s_q5[ch * 8 + c8] * u[j];
            #pragma unroll
            for (int i = 0; i < 8; i++) Sacc[i * 4 + j] += r8[i] * bc;
        }
    }
    __syncthreads();
    // d=5 (leaves): leaf-lgb from registers
    #pragma unroll
    for (int it = 0; it < 2; ++it) {
        const int p = (it * 256 + t) >> 3;
        float r8[8], u[4];
        #pragma unroll
        for (int i = 0; i < 8; i++) r8[i] = s_r5[p * 8 + i];
        down_u(r8, aspR, u);
        #pragma unroll
        for (int j = 0; j < 4; j++) {
            const int q = 4 * p + j;
            const float bc = s_blf[q * 8 + c8];
            const float e6 = bc * u[j];
            pB += e6 * (rL[it * 4 + j] - ldc8);
            pPi += e6 * s_lpi[c8 * 4 + j];
            #pragma unroll
            for (int i = 0; i < 8; i++) Sacc[i * 4 + j] += r8[i] * bc;
        }
    }

    // ---- epilogue: reduce, publish per-s slots (value == ready flag) ----
    #pragma unroll
    for (int z = 0; z < 32; z++) {
        float v = Sacc[z];
        v += __shfl_xor(v, 8);
        v += __shfl_xor(v, 16);
        v += __shfl_xor(v, 32);
        Sacc[z] = v;
    }
    #pragma unroll
    for (int m = 1; m < 64; m <<= 1) { pB += __shfl_xor(pB, m); pPi += __shfl_xor(pPi, m); }
    float* s_stage = s_blf;                       // alias: blf dead after d5
    __syncthreads();
    if (lane < 8) {
        #pragma unroll
        for (int z = 0; z < 32; z++)
            s_stage[wv * 256 + ((z >> 2) * 8 + lane) * 4 + (z & 3)] = Sacc[z];
    }
    if (lane == 0) { s_scal[wv] = pB; s_scal[4 + wv] = pPi; }
    __syncthreads();
    {
        const float TS = s_stage[t] + s_stage[256 + t] + s_stage[512 + t] + s_stage[768 + t];
        float* SgW = ws + WS_SG + ((size_t)(b * 16 + g) * 16 + s) * 256;
        atomicExch(&SgW[t], TS);                  // TS strictly > 0
        float* PgW = ws + WS_PG + ((size_t)(b * 16 + g) * 16 + s) * 2;
        if (t == 0) atomicExch(&PgW[0], s_scal[0] + s_scal[1] + s_scal[2] + s_scal[3]);
        if (t == 1) atomicExch(&PgW[1], s_scal[4] + s_scal[5] + s_scal[6] + s_scal[7]);
    }

    // ---- finalize: block s==15 spin-reads all 16 per-s slots ----
    if (s == 15) {
        if (t < 4) s_Alh[t] = 0.f;
        float Ssum = 0.f;
        float* SgB = ws + WS_SG + (size_t)(b * 16 + g) * 4096;
        #pragma unroll
        for (int sp = 0; sp < 16; ++sp)
            Ssum += spin_pos(&SgB[sp * 256 + t]);
        if (t < 2) {
            float* PgB = ws + WS_PG + (size_t)(b * 16 + g) * 32;
            float tot = 0.f;
            #pragma unroll
            for (int sp = 0; sp < 16; ++sp)
                tot += spin_sent(&PgB[sp * 2 + t]);
            s_scal[8 + t] = tot;
        }
        __syncthreads();
        const float val = s_asp[t] * Ssum;
        atomicAdd(&s_Alh[t & 3], val * ws[WS_LOGA + g * 256 + t]);
        __syncthreads();
        out[(size_t)b * 4096 + t * 16 + g] =
            -(s_Alh[t & 3] + s_scal[8] + s_scal[9] + val * ws[WS_LSP + g * 4 + (t & 3)]);
    }
}

extern "C" void kernel_launch(void* const* d_in, const int* in_sizes, int n_in,
                              void* d_out, int out_size, void* d_ws, size_t ws_size,
                              hipStream_t stream) {
    (void)in_sizes; (void)n_in; (void)out_size; (void)ws_size;
    const int* labels = (const int*)d_in[0];
    const float* A  = (const float*)d_in[1];
    const float* B  = (const float*)d_in[2];
    const float* Pi = (const float*)d_in[3];
    const float* SP = (const float*)d_in[4];
    float* ws = (float*)d_ws;
    float* out = (float*)d_out;

    hipLaunchKernelGGL(k_pre,  dim3(1195), dim3(256), 0, stream, labels, B, ws);
    hipLaunchKernelGGL(k_mid,  dim3(272),  dim3(256), 0, stream, A, B, Pi, SP, ws);
    hipLaunchKernelGGL(k_tree, dim3(1024), dim3(256), 0, stream, labels, B, ws, out);
}